// Round 5
// baseline (696.554 us; speedup 1.0000x reference)
//
#include <hip/hip_runtime.h>
#include <hip/hip_bf16.h>

#define NN 30000          // N_H == N_O
#define DEG 16
#define ZEL (NN * 256)    // floats per node-feature matrix
#define NB1 469           // ceil(NN/64)

typedef __attribute__((ext_vector_type(8))) short bf16x8_t;
typedef __attribute__((ext_vector_type(4))) float f32x4_t;

// ---- bf16 bit helpers (RNE) ----------------------------------------------
__device__ __forceinline__ unsigned short f2bf(float x) {
    unsigned u = __float_as_uint(x);
    return (unsigned short)((u + 0x7FFFu + ((u >> 16) & 1u)) >> 16);
}
__device__ __forceinline__ float bf2f(unsigned short b) {
    return __uint_as_float(((unsigned)b) << 16);
}

// ---------------------------------------------------------------------------
// Weight -> MFMA-frag-friendly hi/lo bf16 layout (unchanged from R4).
// Stored: Bf[(d>>5)*8192 + c*32 + (d&31)]
__global__ void convert_w(const float* __restrict__ W, int isWp,
                          unsigned short* __restrict__ Bhi,
                          unsigned short* __restrict__ Blo) {
    int idx = blockIdx.x * 256 + threadIdx.x;
    if (idx >= 65536) return;
    int d = idx >> 8, c = idx & 255;
    float x;
    if (isWp) x = W[d * 256 + c];
    else { int h = c >> 6, k = c & 63; x = W[h * 16384 + d * 64 + k]; }
    unsigned short hh = f2bf(x);
    unsigned short ll = f2bf(x - bf2f(hh));
    int o = (d >> 5) * 8192 + c * 32 + (d & 31);
    Bhi[o] = hh; Blo[o] = ll;
}

// ---------------------------------------------------------------------------
// u[h*256+d] = sum_k W[h][d][k] * a[h*128 + 64 + k]
__global__ void prep_u(const float* __restrict__ W, const float* __restrict__ a,
                       float* __restrict__ u) {
    int t = threadIdx.x;
    for (int idx = t; idx < 1024; idx += blockDim.x) {
        int h = idx >> 8, d = idx & 255;
        const float* wp = W + (h * 256 + d) * 64;
        const float* ap = a + h * 128 + 64;
        float s = 0.f;
        #pragma unroll 8
        for (int k = 0; k < 64; ++k) s += wp[k] * ap[k];
        u[idx] = s;
    }
}

// ---------------------------------------------------------------------------
// z = concat(f1,f2) @ B  (bf16-split MFMA), A prefetched up-front.
// Fused: s_src[n,h] = z[n]·aL[h]  (from accumulators, shfl-reduced)
//        sd1/sd2[n,h] = concat(f1,f2)[n]·u{1,2}[h]  (from raw A; u1 may be null)
__global__ __launch_bounds__(256)
void gemm_nodes(const float* __restrict__ f1, const float* __restrict__ f2,
                const unsigned short* __restrict__ Bhi,
                const unsigned short* __restrict__ Blo,
                const float* __restrict__ aL,
                float* __restrict__ z, float* __restrict__ s_src,
                const float* __restrict__ u1, const float* __restrict__ u2,
                float* __restrict__ sd1, float* __restrict__ sd2) {
    int t = threadIdx.x, l = t & 63, wv = t >> 6;
    int g = l >> 4, r = l & 15;
    int row0 = blockIdx.x * 64 + wv * 16;
    bool vrow = (row0 + r) < NN;
    int arow = row0 + r; if (arow >= NN) arow = NN - 1;

    // ---- prefetch ALL A fragments (16 float4 in flight) ----
    float4 af[8][2];
    #pragma unroll
    for (int kk = 0; kk < 8; ++kk) {
        int k0 = kk * 32 + g * 8;
        const float* ap = (k0 < 128) ? (f1 + arow * 128 + k0)
                                     : (f2 + arow * 128 + (k0 - 128));
        af[kk][0] = *reinterpret_cast<const float4*>(ap);
        af[kk][1] = *reinterpret_cast<const float4*>(ap + 4);
    }

    // ---- fused dst scores from raw A (call 2 only) ----
    if (u1) {
        float pd1[4] = {0.f,0.f,0.f,0.f}, pd2[4] = {0.f,0.f,0.f,0.f};
        #pragma unroll
        for (int kk = 0; kk < 8; ++kk) {
            int k0 = kk * 32 + g * 8;
            #pragma unroll
            for (int h = 0; h < 4; ++h) {
                float4 ua = *reinterpret_cast<const float4*>(u1 + h * 256 + k0);
                float4 ub = *reinterpret_cast<const float4*>(u1 + h * 256 + k0 + 4);
                pd1[h] += af[kk][0].x*ua.x + af[kk][0].y*ua.y + af[kk][0].z*ua.z + af[kk][0].w*ua.w
                        + af[kk][1].x*ub.x + af[kk][1].y*ub.y + af[kk][1].z*ub.z + af[kk][1].w*ub.w;
                float4 va = *reinterpret_cast<const float4*>(u2 + h * 256 + k0);
                float4 vb = *reinterpret_cast<const float4*>(u2 + h * 256 + k0 + 4);
                pd2[h] += af[kk][0].x*va.x + af[kk][0].y*va.y + af[kk][0].z*va.z + af[kk][0].w*va.w
                        + af[kk][1].x*vb.x + af[kk][1].y*vb.y + af[kk][1].z*vb.z + af[kk][1].w*vb.w;
            }
        }
        #pragma unroll
        for (int m = 16; m < 64; m <<= 1) {
            #pragma unroll
            for (int h = 0; h < 4; ++h) {
                pd1[h] += __shfl_xor(pd1[h], m, 64);
                pd2[h] += __shfl_xor(pd2[h], m, 64);
            }
        }
        if (g == 0 && vrow) {
            #pragma unroll
            for (int h = 0; h < 4; ++h) sd1[arow * 4 + h] = pd1[h];
        }
        if (g == 1 && vrow) {
            #pragma unroll
            for (int h = 0; h < 4; ++h) sd2[arow * 4 + h] = pd2[h];
        }
    }

    // ---- MFMA main loop ----
    f32x4_t acc[16];
    #pragma unroll
    for (int ct = 0; ct < 16; ++ct) acc[ct] = (f32x4_t){0.f, 0.f, 0.f, 0.f};

    for (int kk = 0; kk < 8; ++kk) {
        bf16x8_t ah, al;
        {
            float xs[8] = {af[kk][0].x, af[kk][0].y, af[kk][0].z, af[kk][0].w,
                           af[kk][1].x, af[kk][1].y, af[kk][1].z, af[kk][1].w};
            #pragma unroll
            for (int j = 0; j < 8; ++j) {
                unsigned short h = f2bf(xs[j]);
                ah[j] = (short)h;
                al[j] = (short)f2bf(xs[j] - bf2f(h));
            }
        }
        const unsigned short* bb = Bhi + kk * 8192 + r * 32 + g * 8;
        const unsigned short* bL = Blo + kk * 8192 + r * 32 + g * 8;
        #pragma unroll
        for (int ct = 0; ct < 16; ++ct) {
            bf16x8_t bhv = *reinterpret_cast<const bf16x8_t*>(bb + ct * 512);
            bf16x8_t blv = *reinterpret_cast<const bf16x8_t*>(bL + ct * 512);
            acc[ct] = __builtin_amdgcn_mfma_f32_16x16x32_bf16(ah, bhv, acc[ct], 0, 0, 0);
            acc[ct] = __builtin_amdgcn_mfma_f32_16x16x32_bf16(ah, blv, acc[ct], 0, 0, 0);
            acc[ct] = __builtin_amdgcn_mfma_f32_16x16x32_bf16(al, bhv, acc[ct], 0, 0, 0);
        }
    }

    // ---- z write ----
    int r0 = row0 + g * 4;
    #pragma unroll
    for (int ct = 0; ct < 16; ++ct) {
        int col = ct * 16 + r;
        #pragma unroll
        for (int i = 0; i < 4; ++i) {
            int row = r0 + i;
            if (row < NN) z[row * 256 + col] = acc[ct][i];
        }
    }

    // ---- fused s_src = z · aL  (reduce over 16-lane col groups) ----
    float sc[16];
    #pragma unroll
    for (int j = 0; j < 16; ++j) sc[j] = 0.f;
    #pragma unroll
    for (int ct = 0; ct < 16; ++ct) {
        int h = ct >> 2;
        float coef = aL[h * 128 + (ct & 3) * 16 + r];
        #pragma unroll
        for (int i = 0; i < 4; ++i) sc[h * 4 + i] += acc[ct][i] * coef;
    }
    #pragma unroll
    for (int m = 1; m < 16; m <<= 1) {
        #pragma unroll
        for (int j = 0; j < 16; ++j) sc[j] += __shfl_xor(sc[j], m, 64);
    }
    {   // lane r writes combo (h = r>>2, i = r&3) for its group g
        int h = r >> 2, i = r & 3;
        int row = row0 + g * 4 + i;
        if (row < NN) s_src[row * 4 + h] = sc[r];
    }
}

// ---------------------------------------------------------------------------
// agg: one wave per dst node; output as hi/lo bf16 (unchanged from R4).
__global__ __launch_bounds__(256)
void agg_kernel(const float* __restrict__ z, const float* __restrict__ s_src,
                const float* __restrict__ s_dst, const int* __restrict__ esrc,
                unsigned short* __restrict__ ohi, unsigned short* __restrict__ olo) {
    int wid = (blockIdx.x * blockDim.x + threadIdx.x) >> 6;
    int lane = threadIdx.x & 63;
    if (wid >= NN) return;
    int h = lane >> 4;
    int e = lane & 15;
    int src = esrc[wid * 16 + e];
    float x = s_src[src * 4 + h] + s_dst[wid * 4 + h];
    x = (x >= 0.f) ? x : 0.01f * x;
    float m = x;
    #pragma unroll
    for (int d = 1; d < 16; d <<= 1) m = fmaxf(m, __shfl_xor(m, d, 64));
    float p = __expf(x - m);
    float s = p;
    #pragma unroll
    for (int d = 1; d < 16; d <<= 1) s += __shfl_xor(s, d, 64);
    float alpha = p / s;

    int c = h * 64 + e * 4;
    int gbase = lane & 48;
    float4 acc = make_float4(0.f, 0.f, 0.f, 0.f);
    #pragma unroll
    for (int t = 0; t < 16; ++t) {
        float a = __shfl(alpha, gbase | t, 64);
        int sidx = __shfl(src, gbase | t, 64);
        float4 v = *reinterpret_cast<const float4*>(z + sidx * 256 + c);
        acc.x += a * v.x; acc.y += a * v.y; acc.z += a * v.z; acc.w += a * v.w;
    }
    int base = wid * 256 + c;
    ushort4 hv, lv;
    hv.x = f2bf(acc.x); lv.x = f2bf(acc.x - bf2f(hv.x));
    hv.y = f2bf(acc.y); lv.y = f2bf(acc.y - bf2f(hv.y));
    hv.z = f2bf(acc.z); lv.z = f2bf(acc.z - bf2f(hv.z));
    hv.w = f2bf(acc.w); lv.w = f2bf(acc.w - bf2f(hv.w));
    *reinterpret_cast<ushort4*>(ohi + base) = hv;
    *reinterpret_cast<ushort4*>(olo + base) = lv;
}

// ---------------------------------------------------------------------------
// proj: blocks [0,NB1) -> h1, [NB1,2*NB1) -> h2. A prefetched up-front.
__global__ __launch_bounds__(256)
void gemm_proj(const unsigned short* __restrict__ hhi1, const unsigned short* __restrict__ hlo1,
               const unsigned short* __restrict__ hhi2, const unsigned short* __restrict__ hlo2,
               const unsigned short* __restrict__ Bhi, const unsigned short* __restrict__ Blo,
               const float* __restrict__ bp, const float* __restrict__ wp2v,
               float* __restrict__ wacc) {
    int t = threadIdx.x, l = t & 63, wv = t >> 6;
    int g = l >> 4, r = l & 15;
    int bid = blockIdx.x;
    int e = (bid >= NB1) ? 1 : 0;
    int nb = bid - e * NB1;
    const unsigned short* Ah = e ? hhi2 : hhi1;
    const unsigned short* Al = e ? hlo2 : hlo1;
    int n0 = nb * 64 + wv * 16;
    int nA = n0 + r; if (nA >= NN) nA = NN - 1;
    const unsigned short* Ahp = Ah + (size_t)nA * 256;
    const unsigned short* Alp = Al + (size_t)nA * 256;

    bf16x8_t ahf[8], alf[8];
    #pragma unroll
    for (int kk = 0; kk < 8; ++kk) {
        ahf[kk] = *reinterpret_cast<const bf16x8_t*>(Ahp + kk * 32 + g * 8);
        alf[kk] = *reinterpret_cast<const bf16x8_t*>(Alp + kk * 32 + g * 8);
    }

    f32x4_t acc[16];
    #pragma unroll
    for (int ct = 0; ct < 16; ++ct) acc[ct] = (f32x4_t){0.f, 0.f, 0.f, 0.f};

    for (int kk = 0; kk < 8; ++kk) {
        const unsigned short* bb = Bhi + kk * 8192 + r * 32 + g * 8;
        const unsigned short* bL = Blo + kk * 8192 + r * 32 + g * 8;
        bf16x8_t ah = ahf[kk], al = alf[kk];
        #pragma unroll
        for (int ct = 0; ct < 16; ++ct) {
            bf16x8_t bhv = *reinterpret_cast<const bf16x8_t*>(bb + ct * 512);
            bf16x8_t blv = *reinterpret_cast<const bf16x8_t*>(bL + ct * 512);
            acc[ct] = __builtin_amdgcn_mfma_f32_16x16x32_bf16(ah, bhv, acc[ct], 0, 0, 0);
            acc[ct] = __builtin_amdgcn_mfma_f32_16x16x32_bf16(ah, blv, acc[ct], 0, 0, 0);
            acc[ct] = __builtin_amdgcn_mfma_f32_16x16x32_bf16(al, bhv, acc[ct], 0, 0, 0);
        }
    }

    float part = 0.f;
    #pragma unroll
    for (int ct = 0; ct < 16; ++ct) {
        int col = ct * 16 + r;
        float b = bp[col], w = wp2v[col];
        #pragma unroll
        for (int i = 0; i < 4; ++i) {
            int n = n0 + g * 4 + i;
            if (n < NN) {
                float x = acc[ct][i] + b;
                float tnh = 1.f - 2.f / (__expf(2.f * x) + 1.f);
                part += tnh * w;
            }
        }
    }
    #pragma unroll
    for (int d = 1; d < 64; d <<= 1) part += __shfl_xor(part, d, 64);
    __shared__ float red[4];
    if (l == 0) red[wv] = part;
    __syncthreads();
    if (t == 0) atomicAdd(wacc + e, red[0] + red[1] + red[2] + red[3]);
}

// ---------------------------------------------------------------------------
__global__ __launch_bounds__(256)
void combine_kernel(const unsigned short* __restrict__ hhi1, const unsigned short* __restrict__ hlo1,
                    const unsigned short* __restrict__ hhi2, const unsigned short* __restrict__ hlo2,
                    const float* __restrict__ wacc, float* __restrict__ out) {
    int idx = blockIdx.x * blockDim.x + threadIdx.x;
    if (idx >= NN * 64) return;
    float w0 = wacc[0] * (1.f / 30000.f), w1 = wacc[1] * (1.f / 30000.f);
    float mx = fmaxf(w0, w1);
    float e0 = __expf(w0 - mx), e1 = __expf(w1 - mx);
    float inv = 1.f / (e0 + e1);
    float b0 = e0 * inv, b1 = e1 * inv;
    int base = idx * 4;
    ushort4 h1v = *reinterpret_cast<const ushort4*>(hhi1 + base);
    ushort4 l1v = *reinterpret_cast<const ushort4*>(hlo1 + base);
    ushort4 h2v = *reinterpret_cast<const ushort4*>(hhi2 + base);
    ushort4 l2v = *reinterpret_cast<const ushort4*>(hlo2 + base);
    float4 o;
    o.x = b0 * (bf2f(h1v.x) + bf2f(l1v.x)) + b1 * (bf2f(h2v.x) + bf2f(l2v.x));
    o.y = b0 * (bf2f(h1v.y) + bf2f(l1v.y)) + b1 * (bf2f(h2v.y) + bf2f(l2v.y));
    o.z = b0 * (bf2f(h1v.z) + bf2f(l1v.z)) + b1 * (bf2f(h2v.z) + bf2f(l2v.z));
    o.w = b0 * (bf2f(h1v.w) + bf2f(l1v.w)) + b1 * (bf2f(h2v.w) + bf2f(l2v.w));
    *reinterpret_cast<float4*>(out + base) = o;
}

// ---------------------------------------------------------------------------
extern "C" void kernel_launch(void* const* d_in, const int* in_sizes, int n_in,
                              void* d_out, int out_size, void* d_ws, size_t ws_size,
                              hipStream_t stream) {
    const float* embed_h = (const float*)d_in[0];
    const float* gru_h   = (const float*)d_in[1];
    const float* embed_o = (const float*)d_in[2];
    const float* gru_o   = (const float*)d_in[3];
    const float* W_src1  = (const float*)d_in[4];
    const float* W_dst1  = (const float*)d_in[5];
    const float* a1      = (const float*)d_in[6];
    const float* W_in2   = (const float*)d_in[7];
    const float* a2      = (const float*)d_in[8];
    const float* Wp1     = (const float*)d_in[9];
    const float* bp1     = (const float*)d_in[10];
    const float* wp2     = (const float*)d_in[11];
    const int*   e1_src  = (const int*)d_in[12];
    const int*   e2_src  = (const int*)d_in[14];
    float* out = (float*)d_out;

    float* ws = (float*)d_ws;
    float* zs = ws;                               // [0, ZEL) f32
    float* z2 = ws + (size_t)ZEL;                 // [ZEL, 2ZEL) f32
    unsigned short* hhi1 = (unsigned short*)(ws + (size_t)2 * ZEL);
    unsigned short* hlo1 = hhi1 + (size_t)ZEL;
    unsigned short* hhi2 = (unsigned short*)ws;   // reuse zs (dead after agg1)
    unsigned short* hlo2 = hhi2 + (size_t)ZEL;

    float* tail  = ws + (size_t)3 * ZEL;
    float* ssrc  = tail;
    float* sdst  = ssrc + NN * 4;
    float* ssrc2 = ssrc + NN * 8;
    float* sdst2 = ssrc + NN * 12;
    float* u1    = ssrc + NN * 16;
    float* u2    = u1 + 1024;
    float* wacc  = u2 + 1024;
    unsigned short* Bhi1 = (unsigned short*)(wacc + 2);
    unsigned short* Blo1 = Bhi1 + 65536;
    unsigned short* Bhi2 = Blo1 + 65536;
    unsigned short* Blo2 = Bhi2 + 65536;
    unsigned short* Bhip = Blo2 + 65536;
    unsigned short* Blop = Bhip + 65536;

    convert_w<<<256, 256, 0, stream>>>(W_src1, 0, Bhi1, Blo1);
    convert_w<<<256, 256, 0, stream>>>(W_in2,  0, Bhi2, Blo2);
    convert_w<<<256, 256, 0, stream>>>(Wp1,    1, Bhip, Blop);
    prep_u<<<1, 256, 0, stream>>>(W_dst1, a1, u1);
    prep_u<<<1, 256, 0, stream>>>(W_in2,  a2, u2);

    // layer-1 src features: z_s + fused s_src
    gemm_nodes<<<NB1, 256, 0, stream>>>(embed_h, gru_h, Bhi1, Blo1, a1,
                                        zs, ssrc, nullptr, nullptr, nullptr, nullptr);
    // layer-2 (dst) features: z2 + fused s_src2 + s_dst (u1) + s_dst2 (u2)
    gemm_nodes<<<NB1, 256, 0, stream>>>(embed_o, gru_o, Bhi2, Blo2, a2,
                                        z2, ssrc2, u1, u2, sdst, sdst2);

    int wave_blocks = (NN * 64 + 255) / 256;
    agg_kernel<<<wave_blocks, 256, 0, stream>>>(zs, ssrc, sdst, e1_src, hhi1, hlo1);
    agg_kernel<<<wave_blocks, 256, 0, stream>>>(z2, ssrc2, sdst2, e2_src, hhi2, hlo2);

    hipMemsetAsync(wacc, 0, 2 * sizeof(float), stream);
    gemm_proj<<<2 * NB1, 256, 0, stream>>>(hhi1, hlo1, hhi2, hlo2,
                                           Bhip, Blop, bp1, wp2, wacc);

    combine_kernel<<<(NN * 64 + 255) / 256, 256, 0, stream>>>(hhi1, hlo1, hhi2, hlo2,
                                                              wacc, out);
}

// Round 8
// 568.912 us; speedup vs baseline: 1.2244x; 1.2244x over previous
//
#include <hip/hip_runtime.h>
#include <hip/hip_bf16.h>

#define NN 30000          // N_H == N_O
#define DEG 16
#define ZEL (NN * 256)    // floats per node-feature matrix
#define NB1 469           // ceil(NN/64)

typedef __attribute__((ext_vector_type(8))) short bf16x8_t;
typedef __attribute__((ext_vector_type(4))) float f32x4_t;

// ---- bf16 bit helpers (RNE) ----------------------------------------------
__device__ __forceinline__ unsigned short f2bf(float x) {
    unsigned u = __float_as_uint(x);
    return (unsigned short)((u + 0x7FFFu + ((u >> 16) & 1u)) >> 16);
}
__device__ __forceinline__ float bf2f(unsigned short b) {
    return __uint_as_float(((unsigned)b) << 16);
}

// ---------------------------------------------------------------------------
// Weight -> MFMA-frag-friendly hi/lo bf16 layout.
// Stored: Bf[(d>>5)*8192 + c*32 + (d&31)]
__global__ void convert_w(const float* __restrict__ W, int isWp,
                          unsigned short* __restrict__ Bhi,
                          unsigned short* __restrict__ Blo) {
    int idx = blockIdx.x * 256 + threadIdx.x;
    if (idx >= 65536) return;
    int d = idx >> 8, c = idx & 255;
    float x;
    if (isWp) x = W[d * 256 + c];
    else { int h = c >> 6, k = c & 63; x = W[h * 16384 + d * 64 + k]; }
    unsigned short hh = f2bf(x);
    unsigned short ll = f2bf(x - bf2f(hh));
    int o = (d >> 5) * 8192 + c * 32 + (d & 31);
    Bhi[o] = hh; Blo[o] = ll;
}

// ---------------------------------------------------------------------------
// u[h*256+d] = sum_k W[h][d][k] * a[h*128 + 64 + k]
__global__ void prep_u(const float* __restrict__ W, const float* __restrict__ a,
                       float* __restrict__ u) {
    int t = threadIdx.x;
    for (int idx = t; idx < 1024; idx += blockDim.x) {
        int h = idx >> 8, d = idx & 255;
        const float* wp = W + (h * 256 + d) * 64;
        const float* ap = a + h * 128 + 64;
        float s = 0.f;
        #pragma unroll 8
        for (int k = 0; k < 64; ++k) s += wp[k] * ap[k];
        u[idx] = s;
    }
}

// ---------------------------------------------------------------------------
// z = concat(f1,f2) @ B  (bf16-split MFMA), A prefetched up-front.
// Fused: s_src[n,h] = z[n]·aL[h]; sd1/sd2[n,h] = A[n]·u{1,2}[h] (u1 may be null)
__global__ __launch_bounds__(256)
void gemm_nodes(const float* __restrict__ f1, const float* __restrict__ f2,
                const unsigned short* __restrict__ Bhi,
                const unsigned short* __restrict__ Blo,
                const float* __restrict__ aL,
                float* __restrict__ z, float* __restrict__ s_src,
                const float* __restrict__ u1, const float* __restrict__ u2,
                float* __restrict__ sd1, float* __restrict__ sd2) {
    int t = threadIdx.x, l = t & 63, wv = t >> 6;
    int g = l >> 4, r = l & 15;
    int row0 = blockIdx.x * 64 + wv * 16;
    bool vrow = (row0 + r) < NN;
    int arow = row0 + r; if (arow >= NN) arow = NN - 1;

    // ---- prefetch ALL A fragments (16 float4 in flight) ----
    float4 af[8][2];
    #pragma unroll
    for (int kk = 0; kk < 8; ++kk) {
        int k0 = kk * 32 + g * 8;
        const float* ap = (k0 < 128) ? (f1 + arow * 128 + k0)
                                     : (f2 + arow * 128 + (k0 - 128));
        af[kk][0] = *reinterpret_cast<const float4*>(ap);
        af[kk][1] = *reinterpret_cast<const float4*>(ap + 4);
    }

    // ---- fused dst scores from raw A (call 2 only) ----
    if (u1) {
        float pd1[4] = {0.f,0.f,0.f,0.f}, pd2[4] = {0.f,0.f,0.f,0.f};
        #pragma unroll
        for (int kk = 0; kk < 8; ++kk) {
            int k0 = kk * 32 + g * 8;
            #pragma unroll
            for (int h = 0; h < 4; ++h) {
                float4 ua = *reinterpret_cast<const float4*>(u1 + h * 256 + k0);
                float4 ub = *reinterpret_cast<const float4*>(u1 + h * 256 + k0 + 4);
                pd1[h] += af[kk][0].x*ua.x + af[kk][0].y*ua.y + af[kk][0].z*ua.z + af[kk][0].w*ua.w
                        + af[kk][1].x*ub.x + af[kk][1].y*ub.y + af[kk][1].z*ub.z + af[kk][1].w*ub.w;
                float4 va = *reinterpret_cast<const float4*>(u2 + h * 256 + k0);
                float4 vb = *reinterpret_cast<const float4*>(u2 + h * 256 + k0 + 4);
                pd2[h] += af[kk][0].x*va.x + af[kk][0].y*va.y + af[kk][0].z*va.z + af[kk][0].w*va.w
                        + af[kk][1].x*vb.x + af[kk][1].y*vb.y + af[kk][1].z*vb.z + af[kk][1].w*vb.w;
            }
        }
        #pragma unroll
        for (int m = 16; m < 64; m <<= 1) {
            #pragma unroll
            for (int h = 0; h < 4; ++h) {
                pd1[h] += __shfl_xor(pd1[h], m, 64);
                pd2[h] += __shfl_xor(pd2[h], m, 64);
            }
        }
        if (g == 0 && vrow) {
            #pragma unroll
            for (int h = 0; h < 4; ++h) sd1[arow * 4 + h] = pd1[h];
        }
        if (g == 1 && vrow) {
            #pragma unroll
            for (int h = 0; h < 4; ++h) sd2[arow * 4 + h] = pd2[h];
        }
    }

    // ---- MFMA main loop (MUST be unrolled: af[kk] indexing — rule #20) ----
    f32x4_t acc[16];
    #pragma unroll
    for (int ct = 0; ct < 16; ++ct) acc[ct] = (f32x4_t){0.f, 0.f, 0.f, 0.f};

    #pragma unroll
    for (int kk = 0; kk < 8; ++kk) {
        bf16x8_t ah, al;
        {
            float xs[8] = {af[kk][0].x, af[kk][0].y, af[kk][0].z, af[kk][0].w,
                           af[kk][1].x, af[kk][1].y, af[kk][1].z, af[kk][1].w};
            #pragma unroll
            for (int j = 0; j < 8; ++j) {
                unsigned short h = f2bf(xs[j]);
                ah[j] = (short)h;
                al[j] = (short)f2bf(xs[j] - bf2f(h));
            }
        }
        const unsigned short* bb = Bhi + kk * 8192 + r * 32 + g * 8;
        const unsigned short* bL = Blo + kk * 8192 + r * 32 + g * 8;
        #pragma unroll
        for (int ct = 0; ct < 16; ++ct) {
            bf16x8_t bhv = *reinterpret_cast<const bf16x8_t*>(bb + ct * 512);
            bf16x8_t blv = *reinterpret_cast<const bf16x8_t*>(bL + ct * 512);
            acc[ct] = __builtin_amdgcn_mfma_f32_16x16x32_bf16(ah, bhv, acc[ct], 0, 0, 0);
            acc[ct] = __builtin_amdgcn_mfma_f32_16x16x32_bf16(ah, blv, acc[ct], 0, 0, 0);
            acc[ct] = __builtin_amdgcn_mfma_f32_16x16x32_bf16(al, bhv, acc[ct], 0, 0, 0);
        }
    }

    // ---- z write ----
    int r0 = row0 + g * 4;
    #pragma unroll
    for (int ct = 0; ct < 16; ++ct) {
        int col = ct * 16 + r;
        #pragma unroll
        for (int i = 0; i < 4; ++i) {
            int row = r0 + i;
            if (row < NN) z[row * 256 + col] = acc[ct][i];
        }
    }

    // ---- fused s_src = z · aL  (reduce over 16-lane col groups) ----
    float sc[16];
    #pragma unroll
    for (int j = 0; j < 16; ++j) sc[j] = 0.f;
    #pragma unroll
    for (int ct = 0; ct < 16; ++ct) {
        int h = ct >> 2;
        float coef = aL[h * 128 + (ct & 3) * 16 + r];
        #pragma unroll
        for (int i = 0; i < 4; ++i) sc[h * 4 + i] += acc[ct][i] * coef;
    }
    #pragma unroll
    for (int m = 1; m < 16; m <<= 1) {
        #pragma unroll
        for (int j = 0; j < 16; ++j) sc[j] += __shfl_xor(sc[j], m, 64);
    }
    {   // lane r writes combo (h = r>>2, i = r&3) for its group g
        int h = r >> 2, i = r & 3;
        int row = row0 + g * 4 + i;
        if (row < NN) s_src[row * 4 + h] = sc[r];
    }
}

// ---------------------------------------------------------------------------
// agg: one wave per dst node; output as hi/lo bf16.
__global__ __launch_bounds__(256)
void agg_kernel(const float* __restrict__ z, const float* __restrict__ s_src,
                const float* __restrict__ s_dst, const int* __restrict__ esrc,
                unsigned short* __restrict__ ohi, unsigned short* __restrict__ olo) {
    int wid = (blockIdx.x * blockDim.x + threadIdx.x) >> 6;
    int lane = threadIdx.x & 63;
    if (wid >= NN) return;
    int h = lane >> 4;
    int e = lane & 15;
    int src = esrc[wid * 16 + e];
    float x = s_src[src * 4 + h] + s_dst[wid * 4 + h];
    x = (x >= 0.f) ? x : 0.01f * x;
    float m = x;
    #pragma unroll
    for (int d = 1; d < 16; d <<= 1) m = fmaxf(m, __shfl_xor(m, d, 64));
    float p = __expf(x - m);
    float s = p;
    #pragma unroll
    for (int d = 1; d < 16; d <<= 1) s += __shfl_xor(s, d, 64);
    float alpha = p / s;

    int c = h * 64 + e * 4;
    int gbase = lane & 48;
    float4 acc = make_float4(0.f, 0.f, 0.f, 0.f);
    #pragma unroll
    for (int t = 0; t < 16; ++t) {
        float a = __shfl(alpha, gbase | t, 64);
        int sidx = __shfl(src, gbase | t, 64);
        float4 v = *reinterpret_cast<const float4*>(z + sidx * 256 + c);
        acc.x += a * v.x; acc.y += a * v.y; acc.z += a * v.z; acc.w += a * v.w;
    }
    int base = wid * 256 + c;
    ushort4 hv, lv;
    hv.x = f2bf(acc.x); lv.x = f2bf(acc.x - bf2f(hv.x));
    hv.y = f2bf(acc.y); lv.y = f2bf(acc.y - bf2f(hv.y));
    hv.z = f2bf(acc.z); lv.z = f2bf(acc.z - bf2f(hv.z));
    hv.w = f2bf(acc.w); lv.w = f2bf(acc.w - bf2f(hv.w));
    *reinterpret_cast<ushort4*>(ohi + base) = hv;
    *reinterpret_cast<ushort4*>(olo + base) = lv;
}

// ---------------------------------------------------------------------------
// proj: blocks [0,NB1) -> h1, [NB1,2*NB1) -> h2. A prefetched up-front.
__global__ __launch_bounds__(256)
void gemm_proj(const unsigned short* __restrict__ hhi1, const unsigned short* __restrict__ hlo1,
               const unsigned short* __restrict__ hhi2, const unsigned short* __restrict__ hlo2,
               const unsigned short* __restrict__ Bhi, const unsigned short* __restrict__ Blo,
               const float* __restrict__ bp, const float* __restrict__ wp2v,
               float* __restrict__ wacc) {
    int t = threadIdx.x, l = t & 63, wv = t >> 6;
    int g = l >> 4, r = l & 15;
    int bid = blockIdx.x;
    int e = (bid >= NB1) ? 1 : 0;
    int nb = bid - e * NB1;
    const unsigned short* Ah = e ? hhi2 : hhi1;
    const unsigned short* Al = e ? hlo2 : hlo1;
    int n0 = nb * 64 + wv * 16;
    int nA = n0 + r; if (nA >= NN) nA = NN - 1;
    const unsigned short* Ahp = Ah + (size_t)nA * 256;
    const unsigned short* Alp = Al + (size_t)nA * 256;

    bf16x8_t ahf[8], alf[8];
    #pragma unroll
    for (int kk = 0; kk < 8; ++kk) {
        ahf[kk] = *reinterpret_cast<const bf16x8_t*>(Ahp + kk * 32 + g * 8);
        alf[kk] = *reinterpret_cast<const bf16x8_t*>(Alp + kk * 32 + g * 8);
    }

    f32x4_t acc[16];
    #pragma unroll
    for (int ct = 0; ct < 16; ++ct) acc[ct] = (f32x4_t){0.f, 0.f, 0.f, 0.f};

    // MUST be unrolled: ahf[kk]/alf[kk] indexing (rule #20)
    #pragma unroll
    for (int kk = 0; kk < 8; ++kk) {
        const unsigned short* bb = Bhi + kk * 8192 + r * 32 + g * 8;
        const unsigned short* bL = Blo + kk * 8192 + r * 32 + g * 8;
        bf16x8_t ah = ahf[kk], al = alf[kk];
        #pragma unroll
        for (int ct = 0; ct < 16; ++ct) {
            bf16x8_t bhv = *reinterpret_cast<const bf16x8_t*>(bb + ct * 512);
            bf16x8_t blv = *reinterpret_cast<const bf16x8_t*>(bL + ct * 512);
            acc[ct] = __builtin_amdgcn_mfma_f32_16x16x32_bf16(ah, bhv, acc[ct], 0, 0, 0);
            acc[ct] = __builtin_amdgcn_mfma_f32_16x16x32_bf16(ah, blv, acc[ct], 0, 0, 0);
            acc[ct] = __builtin_amdgcn_mfma_f32_16x16x32_bf16(al, bhv, acc[ct], 0, 0, 0);
        }
    }

    float part = 0.f;
    #pragma unroll
    for (int ct = 0; ct < 16; ++ct) {
        int col = ct * 16 + r;
        float b = bp[col], w = wp2v[col];
        #pragma unroll
        for (int i = 0; i < 4; ++i) {
            int n = n0 + g * 4 + i;
            if (n < NN) {
                float x = acc[ct][i] + b;
                float tnh = 1.f - 2.f / (__expf(2.f * x) + 1.f);
                part += tnh * w;
            }
        }
    }
    #pragma unroll
    for (int d = 1; d < 64; d <<= 1) part += __shfl_xor(part, d, 64);
    __shared__ float red[4];
    if (l == 0) red[wv] = part;
    __syncthreads();
    if (t == 0) atomicAdd(wacc + e, red[0] + red[1] + red[2] + red[3]);
}

// ---------------------------------------------------------------------------
__global__ __launch_bounds__(256)
void combine_kernel(const unsigned short* __restrict__ hhi1, const unsigned short* __restrict__ hlo1,
                    const unsigned short* __restrict__ hhi2, const unsigned short* __restrict__ hlo2,
                    const float* __restrict__ wacc, float* __restrict__ out) {
    int idx = blockIdx.x * blockDim.x + threadIdx.x;
    if (idx >= NN * 64) return;
    float w0 = wacc[0] * (1.f / 30000.f), w1 = wacc[1] * (1.f / 30000.f);
    float mx = fmaxf(w0, w1);
    float e0 = __expf(w0 - mx), e1 = __expf(w1 - mx);
    float inv = 1.f / (e0 + e1);
    float b0 = e0 * inv, b1 = e1 * inv;
    int base = idx * 4;
    ushort4 h1v = *reinterpret_cast<const ushort4*>(hhi1 + base);
    ushort4 l1v = *reinterpret_cast<const ushort4*>(hlo1 + base);
    ushort4 h2v = *reinterpret_cast<const ushort4*>(hhi2 + base);
    ushort4 l2v = *reinterpret_cast<const ushort4*>(hlo2 + base);
    float4 o;
    o.x = b0 * (bf2f(h1v.x) + bf2f(l1v.x)) + b1 * (bf2f(h2v.x) + bf2f(l2v.x));
    o.y = b0 * (bf2f(h1v.y) + bf2f(l1v.y)) + b1 * (bf2f(h2v.y) + bf2f(l2v.y));
    o.z = b0 * (bf2f(h1v.z) + bf2f(l1v.z)) + b1 * (bf2f(h2v.z) + bf2f(l2v.z));
    o.w = b0 * (bf2f(h1v.w) + bf2f(l1v.w)) + b1 * (bf2f(h2v.w) + bf2f(l2v.w));
    *reinterpret_cast<float4*>(out + base) = o;
}

// ---------------------------------------------------------------------------
extern "C" void kernel_launch(void* const* d_in, const int* in_sizes, int n_in,
                              void* d_out, int out_size, void* d_ws, size_t ws_size,
                              hipStream_t stream) {
    const float* embed_h = (const float*)d_in[0];
    const float* gru_h   = (const float*)d_in[1];
    const float* embed_o = (const float*)d_in[2];
    const float* gru_o   = (const float*)d_in[3];
    const float* W_src1  = (const float*)d_in[4];
    const float* W_dst1  = (const float*)d_in[5];
    const float* a1      = (const float*)d_in[6];
    const float* W_in2   = (const float*)d_in[7];
    const float* a2      = (const float*)d_in[8];
    const float* Wp1     = (const float*)d_in[9];
    const float* bp1     = (const float*)d_in[10];
    const float* wp2     = (const float*)d_in[11];
    const int*   e1_src  = (const int*)d_in[12];
    const int*   e2_src  = (const int*)d_in[14];
    float* out = (float*)d_out;

    float* ws = (float*)d_ws;
    float* zs = ws;                               // [0, ZEL) f32
    float* z2 = ws + (size_t)ZEL;                 // [ZEL, 2ZEL) f32
    unsigned short* hhi1 = (unsigned short*)(ws + (size_t)2 * ZEL);
    unsigned short* hlo1 = hhi1 + (size_t)ZEL;
    unsigned short* hhi2 = (unsigned short*)ws;   // reuse zs (dead after agg1)
    unsigned short* hlo2 = hhi2 + (size_t)ZEL;

    float* tail  = ws + (size_t)3 * ZEL;
    float* ssrc  = tail;
    float* sdst  = ssrc + NN * 4;
    float* ssrc2 = ssrc + NN * 8;
    float* sdst2 = ssrc + NN * 12;
    float* u1    = ssrc + NN * 16;
    float* u2    = u1 + 1024;
    float* wacc  = u2 + 1024;
    unsigned short* Bhi1 = (unsigned short*)(wacc + 2);
    unsigned short* Blo1 = Bhi1 + 65536;
    unsigned short* Bhi2 = Blo1 + 65536;
    unsigned short* Blo2 = Bhi2 + 65536;
    unsigned short* Bhip = Blo2 + 65536;
    unsigned short* Blop = Bhip + 65536;

    convert_w<<<256, 256, 0, stream>>>(W_src1, 0, Bhi1, Blo1);
    convert_w<<<256, 256, 0, stream>>>(W_in2,  0, Bhi2, Blo2);
    convert_w<<<256, 256, 0, stream>>>(Wp1,    1, Bhip, Blop);
    prep_u<<<1, 256, 0, stream>>>(W_dst1, a1, u1);
    prep_u<<<1, 256, 0, stream>>>(W_in2,  a2, u2);

    // layer-1 src features: z_s + fused s_src
    gemm_nodes<<<NB1, 256, 0, stream>>>(embed_h, gru_h, Bhi1, Blo1, a1,
                                        zs, ssrc, nullptr, nullptr, nullptr, nullptr);
    // layer-2 (dst) features: z2 + fused s_src2 + s_dst (u1) + s_dst2 (u2)
    gemm_nodes<<<NB1, 256, 0, stream>>>(embed_o, gru_o, Bhi2, Blo2, a2,
                                        z2, ssrc2, u1, u2, sdst, sdst2);

    int wave_blocks = (NN * 64 + 255) / 256;
    agg_kernel<<<wave_blocks, 256, 0, stream>>>(zs, ssrc, sdst, e1_src, hhi1, hlo1);
    agg_kernel<<<wave_blocks, 256, 0, stream>>>(z2, ssrc2, sdst2, e2_src, hhi2, hlo2);

    hipMemsetAsync(wacc, 0, 2 * sizeof(float), stream);
    gemm_proj<<<2 * NB1, 256, 0, stream>>>(hhi1, hlo1, hhi2, hlo2,
                                           Bhip, Blop, bp1, wp2, wacc);

    combine_kernel<<<(NN * 64 + 255) / 256, 256, 0, stream>>>(hhi1, hlo1, hhi2, hlo2,
                                                              wacc, out);
}

// Round 9
// 411.107 us; speedup vs baseline: 1.6943x; 1.3839x over previous
//
#include <hip/hip_runtime.h>
#include <hip/hip_bf16.h>

#define NN 30000          // N_H == N_O
#define DEG 16
#define ZEL (NN * 256)    // floats per node-feature matrix
#define NB1 469           // ceil(NN/64)

typedef __attribute__((ext_vector_type(8))) short bf16x8_t;
typedef __attribute__((ext_vector_type(4))) float f32x4_t;

// ---- bf16 bit helpers (RNE) ----------------------------------------------
__device__ __forceinline__ unsigned short f2bf(float x) {
    unsigned u = __float_as_uint(x);
    return (unsigned short)((u + 0x7FFFu + ((u >> 16) & 1u)) >> 16);
}
__device__ __forceinline__ float bf2f(unsigned short b) {
    return __uint_as_float(((unsigned)b) << 16);
}

// ---- async global->LDS 16B copy ------------------------------------------
__device__ __forceinline__ void gl_lds16(const void* g, void* l) {
    __builtin_amdgcn_global_load_lds(
        (const __attribute__((address_space(1))) unsigned int*)g,
        (__attribute__((address_space(3))) unsigned int*)l, 16, 0, 0);
}

// ---------------------------------------------------------------------------
// Weight -> LDS-image hi/lo bf16 layout.
// Logical B[d][c] (d=K 0..255, c=N 0..255).
//   isWp==0: B[d][c] = W[h][d][k], c=h*64+k   (W: [4][256][64])
//   isWp==1: B[d][c] = W[d*256+c]             (Wp1: [256][256])
// Stored element index o (bijection):
//   kk=d>>5, g=(d>>3)&3, j=d&7, ct=c>>4, r=c&15
//   o = kk*8192 + ct*512 + g*128 + r*8 + j
// => per-kk slab (8192 elems = 16KB) is a linear LDS image; lane l=g*16+r
//    reads its bf16x8 frag at byte ct*1024 + l*16.
__global__ void convert_w(const float* __restrict__ W, int isWp,
                          unsigned short* __restrict__ Bhi,
                          unsigned short* __restrict__ Blo) {
    int idx = blockIdx.x * 256 + threadIdx.x;
    if (idx >= 65536) return;
    int d = idx >> 8, c = idx & 255;
    float x;
    if (isWp) x = W[d * 256 + c];
    else { int h = c >> 6, k = c & 63; x = W[h * 16384 + d * 64 + k]; }
    unsigned short hh = f2bf(x);
    unsigned short ll = f2bf(x - bf2f(hh));
    int o = (d >> 5) * 8192 + (c >> 4) * 512 + ((d >> 3) & 3) * 128
          + (c & 15) * 8 + (d & 7);
    Bhi[o] = hh; Blo[o] = ll;
}

// ---------------------------------------------------------------------------
// u[h*256+d] = sum_k W[h][d][k] * a[h*128 + 64 + k]
__global__ void prep_u(const float* __restrict__ W, const float* __restrict__ a,
                       float* __restrict__ u) {
    int t = threadIdx.x;
    for (int idx = t; idx < 1024; idx += blockDim.x) {
        int h = idx >> 8, d = idx & 255;
        const float* wp = W + (h * 256 + d) * 64;
        const float* ap = a + h * 128 + 64;
        float s = 0.f;
        #pragma unroll 8
        for (int k = 0; k < 64; ++k) s += wp[k] * ap[k];
        u[idx] = s;
    }
}

// ---- stage one 16KB hi + 16KB lo slab of B into LDS (async) ---------------
__device__ __forceinline__ void stage_slab(const unsigned short* __restrict__ Bhi,
                                           const unsigned short* __restrict__ Blo,
                                           int kk, unsigned char* smem,
                                           unsigned boff, int t) {
    #pragma unroll
    for (int rd = 0; rd < 4; ++rd) {
        gl_lds16(Bhi + kk * 8192 + rd * 2048 + t * 8,
                 smem + boff + rd * 4096 + t * 16);
        gl_lds16(Blo + kk * 8192 + rd * 2048 + t * 8,
                 smem + boff + 16384 + rd * 4096 + t * 16);
    }
}

// ---------------------------------------------------------------------------
// z = concat(f1,f2) @ B  (bf16-split MFMA). A prefetched to regs; B staged
// to LDS per-kk (double-buffered). Fused: s_src = z·aL; sd1/sd2 = A·u (call 2).
__global__ __launch_bounds__(256)
void gemm_nodes(const float* __restrict__ f1, const float* __restrict__ f2,
                const unsigned short* __restrict__ Bhi,
                const unsigned short* __restrict__ Blo,
                const float* __restrict__ aL,
                float* __restrict__ z, float* __restrict__ s_src,
                const float* __restrict__ u1, const float* __restrict__ u2,
                float* __restrict__ sd1, float* __restrict__ sd2) {
    __shared__ unsigned char smem[65536];       // 2 bufs x (16KB hi + 16KB lo)
    int t = threadIdx.x, l = t & 63, wv = t >> 6;
    int g = l >> 4, r = l & 15;
    int row0 = blockIdx.x * 64 + wv * 16;
    bool vrow = (row0 + r) < NN;
    int arow = row0 + r; if (arow >= NN) arow = NN - 1;

    stage_slab(Bhi, Blo, 0, smem, 0, t);        // issue earliest

    // ---- prefetch ALL A fragments ----
    float4 af[8][2];
    #pragma unroll
    for (int kk = 0; kk < 8; ++kk) {
        int k0 = kk * 32 + g * 8;
        const float* ap = (k0 < 128) ? (f1 + arow * 128 + k0)
                                     : (f2 + arow * 128 + (k0 - 128));
        af[kk][0] = *reinterpret_cast<const float4*>(ap);
        af[kk][1] = *reinterpret_cast<const float4*>(ap + 4);
    }

    // ---- fused dst scores from raw A (call 2 only) ----
    if (u1) {
        float pd1[4] = {0.f,0.f,0.f,0.f}, pd2[4] = {0.f,0.f,0.f,0.f};
        #pragma unroll
        for (int kk = 0; kk < 8; ++kk) {
            int k0 = kk * 32 + g * 8;
            #pragma unroll
            for (int h = 0; h < 4; ++h) {
                float4 ua = *reinterpret_cast<const float4*>(u1 + h * 256 + k0);
                float4 ub = *reinterpret_cast<const float4*>(u1 + h * 256 + k0 + 4);
                pd1[h] += af[kk][0].x*ua.x + af[kk][0].y*ua.y + af[kk][0].z*ua.z + af[kk][0].w*ua.w
                        + af[kk][1].x*ub.x + af[kk][1].y*ub.y + af[kk][1].z*ub.z + af[kk][1].w*ub.w;
                float4 va = *reinterpret_cast<const float4*>(u2 + h * 256 + k0);
                float4 vb = *reinterpret_cast<const float4*>(u2 + h * 256 + k0 + 4);
                pd2[h] += af[kk][0].x*va.x + af[kk][0].y*va.y + af[kk][0].z*va.z + af[kk][0].w*va.w
                        + af[kk][1].x*vb.x + af[kk][1].y*vb.y + af[kk][1].z*vb.z + af[kk][1].w*vb.w;
            }
        }
        #pragma unroll
        for (int m = 16; m < 64; m <<= 1) {
            #pragma unroll
            for (int h = 0; h < 4; ++h) {
                pd1[h] += __shfl_xor(pd1[h], m, 64);
                pd2[h] += __shfl_xor(pd2[h], m, 64);
            }
        }
        if (g == 0 && vrow) {
            #pragma unroll
            for (int h = 0; h < 4; ++h) sd1[arow * 4 + h] = pd1[h];
        }
        if (g == 1 && vrow) {
            #pragma unroll
            for (int h = 0; h < 4; ++h) sd2[arow * 4 + h] = pd2[h];
        }
    }

    // ---- convert A to bf16 hi/lo fragments (af dies here) ----
    bf16x8_t ah[8], al[8];
    #pragma unroll
    for (int kk = 0; kk < 8; ++kk) {
        float xs[8] = {af[kk][0].x, af[kk][0].y, af[kk][0].z, af[kk][0].w,
                       af[kk][1].x, af[kk][1].y, af[kk][1].z, af[kk][1].w};
        #pragma unroll
        for (int j = 0; j < 8; ++j) {
            unsigned short h = f2bf(xs[j]);
            ah[kk][j] = (short)h;
            al[kk][j] = (short)f2bf(xs[j] - bf2f(h));
        }
    }

    f32x4_t acc[16];
    #pragma unroll
    for (int ct = 0; ct < 16; ++ct) acc[ct] = (f32x4_t){0.f, 0.f, 0.f, 0.f};

    // ---- main loop: one barrier per kk, B from LDS (dbuf) ----
    #pragma unroll
    for (int kk = 0; kk < 8; ++kk) {
        __syncthreads();                         // slab kk staged & visible
        if (kk < 7) stage_slab(Bhi, Blo, kk + 1, smem, ((kk + 1) & 1) * 32768u, t);
        const unsigned char* bufp = smem + (kk & 1) * 32768u;
        #pragma unroll
        for (int ct = 0; ct < 16; ++ct) {
            bf16x8_t bhv = *reinterpret_cast<const bf16x8_t*>(bufp + ct * 1024 + l * 16);
            bf16x8_t blv = *reinterpret_cast<const bf16x8_t*>(bufp + 16384 + ct * 1024 + l * 16);
            acc[ct] = __builtin_amdgcn_mfma_f32_16x16x32_bf16(ah[kk], bhv, acc[ct], 0, 0, 0);
            acc[ct] = __builtin_amdgcn_mfma_f32_16x16x32_bf16(ah[kk], blv, acc[ct], 0, 0, 0);
            acc[ct] = __builtin_amdgcn_mfma_f32_16x16x32_bf16(al[kk], bhv, acc[ct], 0, 0, 0);
        }
    }

    // ---- z write ----
    int r0 = row0 + g * 4;
    #pragma unroll
    for (int ct = 0; ct < 16; ++ct) {
        int col = ct * 16 + r;
        #pragma unroll
        for (int i = 0; i < 4; ++i) {
            int row = r0 + i;
            if (row < NN) z[row * 256 + col] = acc[ct][i];
        }
    }

    // ---- fused s_src = z · aL ----
    float sc[16];
    #pragma unroll
    for (int j = 0; j < 16; ++j) sc[j] = 0.f;
    #pragma unroll
    for (int ct = 0; ct < 16; ++ct) {
        int h = ct >> 2;
        float coef = aL[h * 128 + (ct & 3) * 16 + r];
        #pragma unroll
        for (int i = 0; i < 4; ++i) sc[h * 4 + i] += acc[ct][i] * coef;
    }
    #pragma unroll
    for (int m = 1; m < 16; m <<= 1) {
        #pragma unroll
        for (int j = 0; j < 16; ++j) sc[j] += __shfl_xor(sc[j], m, 64);
    }
    {
        int h = r >> 2, i = r & 3;
        int row = row0 + g * 4 + i;
        if (row < NN) s_src[row * 4 + h] = sc[r];
    }
}

// ---------------------------------------------------------------------------
// agg: one wave per dst node; output as hi/lo bf16 (unchanged).
__global__ __launch_bounds__(256)
void agg_kernel(const float* __restrict__ z, const float* __restrict__ s_src,
                const float* __restrict__ s_dst, const int* __restrict__ esrc,
                unsigned short* __restrict__ ohi, unsigned short* __restrict__ olo) {
    int wid = (blockIdx.x * blockDim.x + threadIdx.x) >> 6;
    int lane = threadIdx.x & 63;
    if (wid >= NN) return;
    int h = lane >> 4;
    int e = lane & 15;
    int src = esrc[wid * 16 + e];
    float x = s_src[src * 4 + h] + s_dst[wid * 4 + h];
    x = (x >= 0.f) ? x : 0.01f * x;
    float m = x;
    #pragma unroll
    for (int d = 1; d < 16; d <<= 1) m = fmaxf(m, __shfl_xor(m, d, 64));
    float p = __expf(x - m);
    float s = p;
    #pragma unroll
    for (int d = 1; d < 16; d <<= 1) s += __shfl_xor(s, d, 64);
    float alpha = p / s;

    int c = h * 64 + e * 4;
    int gbase = lane & 48;
    float4 acc = make_float4(0.f, 0.f, 0.f, 0.f);
    #pragma unroll
    for (int t = 0; t < 16; ++t) {
        float a = __shfl(alpha, gbase | t, 64);
        int sidx = __shfl(src, gbase | t, 64);
        float4 v = *reinterpret_cast<const float4*>(z + sidx * 256 + c);
        acc.x += a * v.x; acc.y += a * v.y; acc.z += a * v.z; acc.w += a * v.w;
    }
    int base = wid * 256 + c;
    ushort4 hv, lv;
    hv.x = f2bf(acc.x); lv.x = f2bf(acc.x - bf2f(hv.x));
    hv.y = f2bf(acc.y); lv.y = f2bf(acc.y - bf2f(hv.y));
    hv.z = f2bf(acc.z); lv.z = f2bf(acc.z - bf2f(hv.z));
    hv.w = f2bf(acc.w); lv.w = f2bf(acc.w - bf2f(hv.w));
    *reinterpret_cast<ushort4*>(ohi + base) = hv;
    *reinterpret_cast<ushort4*>(olo + base) = lv;
}

// ---------------------------------------------------------------------------
// proj: blocks [0,NB1) -> h1, [NB1,2*NB1) -> h2. A in regs, B staged to LDS.
__global__ __launch_bounds__(256)
void gemm_proj(const unsigned short* __restrict__ hhi1, const unsigned short* __restrict__ hlo1,
               const unsigned short* __restrict__ hhi2, const unsigned short* __restrict__ hlo2,
               const unsigned short* __restrict__ Bhi, const unsigned short* __restrict__ Blo,
               const float* __restrict__ bp, const float* __restrict__ wp2v,
               float* __restrict__ wacc) {
    __shared__ unsigned char smem[65536];
    int t = threadIdx.x, l = t & 63, wv = t >> 6;
    int g = l >> 4, r = l & 15;
    int bid = blockIdx.x;
    int e = (bid >= NB1) ? 1 : 0;
    int nb = bid - e * NB1;
    const unsigned short* Ah = e ? hhi2 : hhi1;
    const unsigned short* Al = e ? hlo2 : hlo1;
    int n0 = nb * 64 + wv * 16;
    int nA = n0 + r; if (nA >= NN) nA = NN - 1;
    const unsigned short* Ahp = Ah + (size_t)nA * 256;
    const unsigned short* Alp = Al + (size_t)nA * 256;

    stage_slab(Bhi, Blo, 0, smem, 0, t);

    bf16x8_t ahf[8], alf[8];
    #pragma unroll
    for (int kk = 0; kk < 8; ++kk) {
        ahf[kk] = *reinterpret_cast<const bf16x8_t*>(Ahp + kk * 32 + g * 8);
        alf[kk] = *reinterpret_cast<const bf16x8_t*>(Alp + kk * 32 + g * 8);
    }

    f32x4_t acc[16];
    #pragma unroll
    for (int ct = 0; ct < 16; ++ct) acc[ct] = (f32x4_t){0.f, 0.f, 0.f, 0.f};

    #pragma unroll
    for (int kk = 0; kk < 8; ++kk) {
        __syncthreads();
        if (kk < 7) stage_slab(Bhi, Blo, kk + 1, smem, ((kk + 1) & 1) * 32768u, t);
        const unsigned char* bufp = smem + (kk & 1) * 32768u;
        #pragma unroll
        for (int ct = 0; ct < 16; ++ct) {
            bf16x8_t bhv = *reinterpret_cast<const bf16x8_t*>(bufp + ct * 1024 + l * 16);
            bf16x8_t blv = *reinterpret_cast<const bf16x8_t*>(bufp + 16384 + ct * 1024 + l * 16);
            acc[ct] = __builtin_amdgcn_mfma_f32_16x16x32_bf16(ahf[kk], bhv, acc[ct], 0, 0, 0);
            acc[ct] = __builtin_amdgcn_mfma_f32_16x16x32_bf16(ahf[kk], blv, acc[ct], 0, 0, 0);
            acc[ct] = __builtin_amdgcn_mfma_f32_16x16x32_bf16(alf[kk], bhv, acc[ct], 0, 0, 0);
        }
    }

    float part = 0.f;
    #pragma unroll
    for (int ct = 0; ct < 16; ++ct) {
        int col = ct * 16 + r;
        float b = bp[col], w = wp2v[col];
        #pragma unroll
        for (int i = 0; i < 4; ++i) {
            int n = n0 + g * 4 + i;
            if (n < NN) {
                float x = acc[ct][i] + b;
                float tnh = 1.f - 2.f / (__expf(2.f * x) + 1.f);
                part += tnh * w;
            }
        }
    }
    #pragma unroll
    for (int d = 1; d < 64; d <<= 1) part += __shfl_xor(part, d, 64);
    __shared__ float red[4];
    if (l == 0) red[wv] = part;
    __syncthreads();
    if (t == 0) atomicAdd(wacc + e, red[0] + red[1] + red[2] + red[3]);
}

// ---------------------------------------------------------------------------
__global__ __launch_bounds__(256)
void combine_kernel(const unsigned short* __restrict__ hhi1, const unsigned short* __restrict__ hlo1,
                    const unsigned short* __restrict__ hhi2, const unsigned short* __restrict__ hlo2,
                    const float* __restrict__ wacc, float* __restrict__ out) {
    int idx = blockIdx.x * blockDim.x + threadIdx.x;
    if (idx >= NN * 64) return;
    float w0 = wacc[0] * (1.f / 30000.f), w1 = wacc[1] * (1.f / 30000.f);
    float mx = fmaxf(w0, w1);
    float e0 = __expf(w0 - mx), e1 = __expf(w1 - mx);
    float inv = 1.f / (e0 + e1);
    float b0 = e0 * inv, b1 = e1 * inv;
    int base = idx * 4;
    ushort4 h1v = *reinterpret_cast<const ushort4*>(hhi1 + base);
    ushort4 l1v = *reinterpret_cast<const ushort4*>(hlo1 + base);
    ushort4 h2v = *reinterpret_cast<const ushort4*>(hhi2 + base);
    ushort4 l2v = *reinterpret_cast<const ushort4*>(hlo2 + base);
    float4 o;
    o.x = b0 * (bf2f(h1v.x) + bf2f(l1v.x)) + b1 * (bf2f(h2v.x) + bf2f(l2v.x));
    o.y = b0 * (bf2f(h1v.y) + bf2f(l1v.y)) + b1 * (bf2f(h2v.y) + bf2f(l2v.y));
    o.z = b0 * (bf2f(h1v.z) + bf2f(l1v.z)) + b1 * (bf2f(h2v.z) + bf2f(l2v.z));
    o.w = b0 * (bf2f(h1v.w) + bf2f(l1v.w)) + b1 * (bf2f(h2v.w) + bf2f(l2v.w));
    *reinterpret_cast<float4*>(out + base) = o;
}

// ---------------------------------------------------------------------------
extern "C" void kernel_launch(void* const* d_in, const int* in_sizes, int n_in,
                              void* d_out, int out_size, void* d_ws, size_t ws_size,
                              hipStream_t stream) {
    const float* embed_h = (const float*)d_in[0];
    const float* gru_h   = (const float*)d_in[1];
    const float* embed_o = (const float*)d_in[2];
    const float* gru_o   = (const float*)d_in[3];
    const float* W_src1  = (const float*)d_in[4];
    const float* W_dst1  = (const float*)d_in[5];
    const float* a1      = (const float*)d_in[6];
    const float* W_in2   = (const float*)d_in[7];
    const float* a2      = (const float*)d_in[8];
    const float* Wp1     = (const float*)d_in[9];
    const float* bp1     = (const float*)d_in[10];
    const float* wp2     = (const float*)d_in[11];
    const int*   e1_src  = (const int*)d_in[12];
    const int*   e2_src  = (const int*)d_in[14];
    float* out = (float*)d_out;

    float* ws = (float*)d_ws;
    float* zs = ws;                               // [0, ZEL) f32
    float* z2 = ws + (size_t)ZEL;                 // [ZEL, 2ZEL) f32
    unsigned short* hhi1 = (unsigned short*)(ws + (size_t)2 * ZEL);
    unsigned short* hlo1 = hhi1 + (size_t)ZEL;
    unsigned short* hhi2 = (unsigned short*)ws;   // reuse zs (dead after agg1)
    unsigned short* hlo2 = hhi2 + (size_t)ZEL;

    float* tail  = ws + (size_t)3 * ZEL;
    float* ssrc  = tail;
    float* sdst  = ssrc + NN * 4;
    float* ssrc2 = ssrc + NN * 8;
    float* sdst2 = ssrc + NN * 12;
    float* u1    = ssrc + NN * 16;
    float* u2    = u1 + 1024;
    float* wacc  = u2 + 1024;
    unsigned short* Bhi1 = (unsigned short*)(wacc + 2);
    unsigned short* Blo1 = Bhi1 + 65536;
    unsigned short* Bhi2 = Blo1 + 65536;
    unsigned short* Blo2 = Bhi2 + 65536;
    unsigned short* Bhip = Blo2 + 65536;
    unsigned short* Blop = Bhip + 65536;

    convert_w<<<256, 256, 0, stream>>>(W_src1, 0, Bhi1, Blo1);
    convert_w<<<256, 256, 0, stream>>>(W_in2,  0, Bhi2, Blo2);
    convert_w<<<256, 256, 0, stream>>>(Wp1,    1, Bhip, Blop);
    prep_u<<<1, 256, 0, stream>>>(W_dst1, a1, u1);
    prep_u<<<1, 256, 0, stream>>>(W_in2,  a2, u2);

    // layer-1 src features: z_s + fused s_src
    gemm_nodes<<<NB1, 256, 0, stream>>>(embed_h, gru_h, Bhi1, Blo1, a1,
                                        zs, ssrc, nullptr, nullptr, nullptr, nullptr);
    // layer-2 (dst) features: z2 + fused s_src2 + s_dst (u1) + s_dst2 (u2)
    gemm_nodes<<<NB1, 256, 0, stream>>>(embed_o, gru_o, Bhi2, Blo2, a2,
                                        z2, ssrc2, u1, u2, sdst, sdst2);

    int wave_blocks = (NN * 64 + 255) / 256;
    agg_kernel<<<wave_blocks, 256, 0, stream>>>(zs, ssrc, sdst, e1_src, hhi1, hlo1);
    agg_kernel<<<wave_blocks, 256, 0, stream>>>(z2, ssrc2, sdst2, e2_src, hhi2, hlo2);

    hipMemsetAsync(wacc, 0, 2 * sizeof(float), stream);
    gemm_proj<<<2 * NB1, 256, 0, stream>>>(hhi1, hlo1, hhi2, hlo2,
                                           Bhip, Blop, bp1, wp2, wacc);

    combine_kernel<<<(NN * 64 + 255) / 256, 256, 0, stream>>>(hhi1, hlo1, hhi2, hlo2,
                                                              wacc, out);
}

// Round 11
// 340.049 us; speedup vs baseline: 2.0484x; 1.2090x over previous
//
#include <hip/hip_runtime.h>
#include <hip/hip_bf16.h>

#define NN 30000          // N_H == N_O
#define DEG 16
#define ZEL (NN * 256)    // elements per node-feature matrix
#define NB1 469           // ceil(NN/64)

typedef __attribute__((ext_vector_type(8))) short bf16x8_t;
typedef __attribute__((ext_vector_type(4))) float f32x4_t;

// ---- bf16 bit helpers (RNE) ----------------------------------------------
__device__ __forceinline__ unsigned short f2bf(float x) {
    unsigned u = __float_as_uint(x);
    return (unsigned short)((u + 0x7FFFu + ((u >> 16) & 1u)) >> 16);
}
__device__ __forceinline__ float bf2f(unsigned short b) {
    return __uint_as_float(((unsigned)b) << 16);
}

// ---- async global->LDS 16B copy ------------------------------------------
__device__ __forceinline__ void gl_lds16(const void* g, void* l) {
    __builtin_amdgcn_global_load_lds(
        (const __attribute__((address_space(1))) unsigned int*)g,
        (__attribute__((address_space(3))) unsigned int*)l, 16, 0, 0);
}

// ---------------------------------------------------------------------------
// Weight -> LDS-image hi/lo bf16 layout.
//   o = kk*8192 + ct*512 + g*128 + r*8 + j  (kk=d>>5, g=(d>>3)&3, j=d&7,
//                                            ct=c>>4, r=c&15)
__global__ void convert_w(const float* __restrict__ W, int isWp,
                          unsigned short* __restrict__ Bhi,
                          unsigned short* __restrict__ Blo) {
    int idx = blockIdx.x * 256 + threadIdx.x;
    if (idx >= 65536) return;
    int d = idx >> 8, c = idx & 255;
    float x;
    if (isWp) x = W[d * 256 + c];
    else { int h = c >> 6, k = c & 63; x = W[h * 16384 + d * 64 + k]; }
    unsigned short hh = f2bf(x);
    unsigned short ll = f2bf(x - bf2f(hh));
    int o = (d >> 5) * 8192 + (c >> 4) * 512 + ((d >> 3) & 3) * 128
          + (c & 15) * 8 + (d & 7);
    Bhi[o] = hh; Blo[o] = ll;
}

// ---------------------------------------------------------------------------
// u[h*256+d] = sum_k W[h][d][k] * a[h*128 + 64 + k]
__global__ void prep_u(const float* __restrict__ W, const float* __restrict__ a,
                       float* __restrict__ u) {
    int t = threadIdx.x;
    for (int idx = t; idx < 1024; idx += blockDim.x) {
        int h = idx >> 8, d = idx & 255;
        const float* wp = W + (h * 256 + d) * 64;
        const float* ap = a + h * 128 + 64;
        float s = 0.f;
        #pragma unroll 8
        for (int k = 0; k < 64; ++k) s += wp[k] * ap[k];
        u[idx] = s;
    }
}

// ---- stage one 16KB hi + 16KB lo slab of B into LDS (async) ---------------
__device__ __forceinline__ void stage_slab(const unsigned short* __restrict__ Bhi,
                                           const unsigned short* __restrict__ Blo,
                                           int kk, unsigned char* smem,
                                           unsigned boff, int t) {
    #pragma unroll
    for (int rd = 0; rd < 4; ++rd) {
        gl_lds16(Bhi + kk * 8192 + rd * 2048 + t * 8,
                 smem + boff + rd * 4096 + t * 16);
        gl_lds16(Blo + kk * 8192 + rd * 2048 + t * 8,
                 smem + boff + 16384 + rd * 4096 + t * 16);
    }
}

// ---------------------------------------------------------------------------
// z(bf16) = concat(f1,f2) @ B  (bf16-split MFMA). A in regs, B LDS-staged.
// Fused: s_src = z·aL (f32 acc); sd1/sd2 = A·u (call 2).
__global__ __launch_bounds__(256)
void gemm_nodes(const float* __restrict__ f1, const float* __restrict__ f2,
                const unsigned short* __restrict__ Bhi,
                const unsigned short* __restrict__ Blo,
                const float* __restrict__ aL,
                unsigned short* __restrict__ z, float* __restrict__ s_src,
                const float* __restrict__ u1, const float* __restrict__ u2,
                float* __restrict__ sd1, float* __restrict__ sd2) {
    __shared__ unsigned char smem[65536];       // 2 bufs x (16KB hi + 16KB lo)
    int t = threadIdx.x, l = t & 63, wv = t >> 6;
    int g = l >> 4, r = l & 15;
    int row0 = blockIdx.x * 64 + wv * 16;
    bool vrow = (row0 + r) < NN;
    int arow = row0 + r; if (arow >= NN) arow = NN - 1;

    stage_slab(Bhi, Blo, 0, smem, 0, t);        // issue earliest

    // ---- prefetch ALL A fragments ----
    float4 af[8][2];
    #pragma unroll
    for (int kk = 0; kk < 8; ++kk) {
        int k0 = kk * 32 + g * 8;
        const float* ap = (k0 < 128) ? (f1 + arow * 128 + k0)
                                     : (f2 + arow * 128 + (k0 - 128));
        af[kk][0] = *reinterpret_cast<const float4*>(ap);
        af[kk][1] = *reinterpret_cast<const float4*>(ap + 4);
    }

    // ---- fused dst scores from raw A (call 2 only) ----
    if (u1) {
        float pd1[4] = {0.f,0.f,0.f,0.f}, pd2[4] = {0.f,0.f,0.f,0.f};
        #pragma unroll
        for (int kk = 0; kk < 8; ++kk) {
            int k0 = kk * 32 + g * 8;
            #pragma unroll
            for (int h = 0; h < 4; ++h) {
                float4 ua = *reinterpret_cast<const float4*>(u1 + h * 256 + k0);
                float4 ub = *reinterpret_cast<const float4*>(u1 + h * 256 + k0 + 4);
                pd1[h] += af[kk][0].x*ua.x + af[kk][0].y*ua.y + af[kk][0].z*ua.z + af[kk][0].w*ua.w
                        + af[kk][1].x*ub.x + af[kk][1].y*ub.y + af[kk][1].z*ub.z + af[kk][1].w*ub.w;
                float4 va = *reinterpret_cast<const float4*>(u2 + h * 256 + k0);
                float4 vb = *reinterpret_cast<const float4*>(u2 + h * 256 + k0 + 4);
                pd2[h] += af[kk][0].x*va.x + af[kk][0].y*va.y + af[kk][0].z*va.z + af[kk][0].w*va.w
                        + af[kk][1].x*vb.x + af[kk][1].y*vb.y + af[kk][1].z*vb.z + af[kk][1].w*vb.w;
            }
        }
        #pragma unroll
        for (int m = 16; m < 64; m <<= 1) {
            #pragma unroll
            for (int h = 0; h < 4; ++h) {
                pd1[h] += __shfl_xor(pd1[h], m, 64);
                pd2[h] += __shfl_xor(pd2[h], m, 64);
            }
        }
        if (g == 0 && vrow) {
            #pragma unroll
            for (int h = 0; h < 4; ++h) sd1[arow * 4 + h] = pd1[h];
        }
        if (g == 1 && vrow) {
            #pragma unroll
            for (int h = 0; h < 4; ++h) sd2[arow * 4 + h] = pd2[h];
        }
    }

    // ---- convert A to bf16 hi/lo fragments ----
    bf16x8_t ah[8], al[8];
    #pragma unroll
    for (int kk = 0; kk < 8; ++kk) {
        float xs[8] = {af[kk][0].x, af[kk][0].y, af[kk][0].z, af[kk][0].w,
                       af[kk][1].x, af[kk][1].y, af[kk][1].z, af[kk][1].w};
        #pragma unroll
        for (int j = 0; j < 8; ++j) {
            unsigned short h = f2bf(xs[j]);
            ah[kk][j] = (short)h;
            al[kk][j] = (short)f2bf(xs[j] - bf2f(h));
        }
    }

    f32x4_t acc[16];
    #pragma unroll
    for (int ct = 0; ct < 16; ++ct) acc[ct] = (f32x4_t){0.f, 0.f, 0.f, 0.f};

    // ---- main loop: one barrier per kk, B from LDS (dbuf) ----
    #pragma unroll
    for (int kk = 0; kk < 8; ++kk) {
        __syncthreads();
        if (kk < 7) stage_slab(Bhi, Blo, kk + 1, smem, ((kk + 1) & 1) * 32768u, t);
        const unsigned char* bufp = smem + (kk & 1) * 32768u;
        #pragma unroll
        for (int ct = 0; ct < 16; ++ct) {
            bf16x8_t bhv = *reinterpret_cast<const bf16x8_t*>(bufp + ct * 1024 + l * 16);
            bf16x8_t blv = *reinterpret_cast<const bf16x8_t*>(bufp + 16384 + ct * 1024 + l * 16);
            acc[ct] = __builtin_amdgcn_mfma_f32_16x16x32_bf16(ah[kk], bhv, acc[ct], 0, 0, 0);
            acc[ct] = __builtin_amdgcn_mfma_f32_16x16x32_bf16(ah[kk], blv, acc[ct], 0, 0, 0);
            acc[ct] = __builtin_amdgcn_mfma_f32_16x16x32_bf16(al[kk], bhv, acc[ct], 0, 0, 0);
        }
    }

    // ---- z write (bf16) ----
    int r0 = row0 + g * 4;
    #pragma unroll
    for (int ct = 0; ct < 16; ++ct) {
        int col = ct * 16 + r;
        #pragma unroll
        for (int i = 0; i < 4; ++i) {
            int row = r0 + i;
            if (row < NN) z[row * 256 + col] = f2bf(acc[ct][i]);
        }
    }

    // ---- fused s_src = z · aL (from f32 acc) ----
    float sc[16];
    #pragma unroll
    for (int j = 0; j < 16; ++j) sc[j] = 0.f;
    #pragma unroll
    for (int ct = 0; ct < 16; ++ct) {
        int h = ct >> 2;
        float coef = aL[h * 128 + (ct & 3) * 16 + r];
        #pragma unroll
        for (int i = 0; i < 4; ++i) sc[h * 4 + i] += acc[ct][i] * coef;
    }
    #pragma unroll
    for (int m = 1; m < 16; m <<= 1) {
        #pragma unroll
        for (int j = 0; j < 16; ++j) sc[j] += __shfl_xor(sc[j], m, 64);
    }
    {
        int h = r >> 2, i = r & 3;
        int row = row0 + g * 4 + i;
        if (row < NN) s_src[row * 4 + h] = sc[r];
    }
}

// ---------------------------------------------------------------------------
// agg: one wave per dst node; z gathered as bf16 (half bytes); out hi/lo bf16.
__global__ __launch_bounds__(256)
void agg_kernel(const unsigned short* __restrict__ z, const float* __restrict__ s_src,
                const float* __restrict__ s_dst, const int* __restrict__ esrc,
                unsigned short* __restrict__ ohi, unsigned short* __restrict__ olo) {
    int wid = (blockIdx.x * blockDim.x + threadIdx.x) >> 6;
    int lane = threadIdx.x & 63;
    if (wid >= NN) return;
    int h = lane >> 4;
    int e = lane & 15;
    int src = esrc[wid * 16 + e];
    float x = s_src[src * 4 + h] + s_dst[wid * 4 + h];
    x = (x >= 0.f) ? x : 0.01f * x;
    float m = x;
    #pragma unroll
    for (int d = 1; d < 16; d <<= 1) m = fmaxf(m, __shfl_xor(m, d, 64));
    float p = __expf(x - m);
    float s = p;
    #pragma unroll
    for (int d = 1; d < 16; d <<= 1) s += __shfl_xor(s, d, 64);
    float alpha = p / s;

    int c = h * 64 + e * 4;
    int gbase = lane & 48;
    float4 acc = make_float4(0.f, 0.f, 0.f, 0.f);
    #pragma unroll
    for (int t = 0; t < 16; ++t) {
        float a = __shfl(alpha, gbase | t, 64);
        int sidx = __shfl(src, gbase | t, 64);
        ushort4 v = *reinterpret_cast<const ushort4*>(z + sidx * 256 + c);
        acc.x += a * bf2f(v.x); acc.y += a * bf2f(v.y);
        acc.z += a * bf2f(v.z); acc.w += a * bf2f(v.w);
    }
    int base = wid * 256 + c;
    ushort4 hv, lv;
    hv.x = f2bf(acc.x); lv.x = f2bf(acc.x - bf2f(hv.x));
    hv.y = f2bf(acc.y); lv.y = f2bf(acc.y - bf2f(hv.y));
    hv.z = f2bf(acc.z); lv.z = f2bf(acc.z - bf2f(hv.z));
    hv.w = f2bf(acc.w); lv.w = f2bf(acc.w - bf2f(hv.w));
    *reinterpret_cast<ushort4*>(ohi + base) = hv;
    *reinterpret_cast<ushort4*>(olo + base) = lv;
}

// ---------------------------------------------------------------------------
// proj: blocks [0,NB1) -> h1, [NB1,2*NB1) -> h2. A in regs, B LDS-staged.
__global__ __launch_bounds__(256)
void gemm_proj(const unsigned short* __restrict__ hhi1, const unsigned short* __restrict__ hlo1,
               const unsigned short* __restrict__ hhi2, const unsigned short* __restrict__ hlo2,
               const unsigned short* __restrict__ Bhi, const unsigned short* __restrict__ Blo,
               const float* __restrict__ bp, const float* __restrict__ wp2v,
               float* __restrict__ wacc) {
    __shared__ unsigned char smem[65536];
    int t = threadIdx.x, l = t & 63, wv = t >> 6;
    int g = l >> 4, r = l & 15;
    int bid = blockIdx.x;
    int e = (bid >= NB1) ? 1 : 0;
    int nb = bid - e * NB1;
    const unsigned short* Ah = e ? hhi2 : hhi1;
    const unsigned short* Al = e ? hlo2 : hlo1;
    int n0 = nb * 64 + wv * 16;
    int nA = n0 + r; if (nA >= NN) nA = NN - 1;
    const unsigned short* Ahp = Ah + (size_t)nA * 256;
    const unsigned short* Alp = Al + (size_t)nA * 256;

    stage_slab(Bhi, Blo, 0, smem, 0, t);

    bf16x8_t ahf[8], alf[8];
    #pragma unroll
    for (int kk = 0; kk < 8; ++kk) {
        ahf[kk] = *reinterpret_cast<const bf16x8_t*>(Ahp + kk * 32 + g * 8);
        alf[kk] = *reinterpret_cast<const bf16x8_t*>(Alp + kk * 32 + g * 8);
    }

    f32x4_t acc[16];
    #pragma unroll
    for (int ct = 0; ct < 16; ++ct) acc[ct] = (f32x4_t){0.f, 0.f, 0.f, 0.f};

    #pragma unroll
    for (int kk = 0; kk < 8; ++kk) {
        __syncthreads();
        if (kk < 7) stage_slab(Bhi, Blo, kk + 1, smem, ((kk + 1) & 1) * 32768u, t);
        const unsigned char* bufp = smem + (kk & 1) * 32768u;
        #pragma unroll
        for (int ct = 0; ct < 16; ++ct) {
            bf16x8_t bhv = *reinterpret_cast<const bf16x8_t*>(bufp + ct * 1024 + l * 16);
            bf16x8_t blv = *reinterpret_cast<const bf16x8_t*>(bufp + 16384 + ct * 1024 + l * 16);
            acc[ct] = __builtin_amdgcn_mfma_f32_16x16x32_bf16(ahf[kk], bhv, acc[ct], 0, 0, 0);
            acc[ct] = __builtin_amdgcn_mfma_f32_16x16x32_bf16(ahf[kk], blv, acc[ct], 0, 0, 0);
            acc[ct] = __builtin_amdgcn_mfma_f32_16x16x32_bf16(alf[kk], bhv, acc[ct], 0, 0, 0);
        }
    }

    float part = 0.f;
    #pragma unroll
    for (int ct = 0; ct < 16; ++ct) {
        int col = ct * 16 + r;
        float b = bp[col], w = wp2v[col];
        #pragma unroll
        for (int i = 0; i < 4; ++i) {
            int n = n0 + g * 4 + i;
            if (n < NN) {
                float x = acc[ct][i] + b;
                float tnh = 1.f - 2.f / (__expf(2.f * x) + 1.f);
                part += tnh * w;
            }
        }
    }
    #pragma unroll
    for (int d = 1; d < 64; d <<= 1) part += __shfl_xor(part, d, 64);
    __shared__ float red[4];
    if (l == 0) red[wv] = part;
    __syncthreads();
    if (t == 0) atomicAdd(wacc + e, red[0] + red[1] + red[2] + red[3]);
}

// ---------------------------------------------------------------------------
__global__ __launch_bounds__(256)
void combine_kernel(const unsigned short* __restrict__ hhi1, const unsigned short* __restrict__ hlo1,
                    const unsigned short* __restrict__ hhi2, const unsigned short* __restrict__ hlo2,
                    const float* __restrict__ wacc, float* __restrict__ out) {
    int idx = blockIdx.x * blockDim.x + threadIdx.x;
    if (idx >= NN * 64) return;
    float w0 = wacc[0] * (1.f / 30000.f), w1 = wacc[1] * (1.f / 30000.f);
    float mx = fmaxf(w0, w1);
    float e0 = __expf(w0 - mx), e1 = __expf(w1 - mx);
    float inv = 1.f / (e0 + e1);
    float b0 = e0 * inv, b1 = e1 * inv;
    int base = idx * 4;
    ushort4 h1v = *reinterpret_cast<const ushort4*>(hhi1 + base);
    ushort4 l1v = *reinterpret_cast<const ushort4*>(hlo1 + base);
    ushort4 h2v = *reinterpret_cast<const ushort4*>(hhi2 + base);
    ushort4 l2v = *reinterpret_cast<const ushort4*>(hlo2 + base);
    float4 o;
    o.x = b0 * (bf2f(h1v.x) + bf2f(l1v.x)) + b1 * (bf2f(h2v.x) + bf2f(l2v.x));
    o.y = b0 * (bf2f(h1v.y) + bf2f(l1v.y)) + b1 * (bf2f(h2v.y) + bf2f(l2v.y));
    o.z = b0 * (bf2f(h1v.z) + bf2f(l1v.z)) + b1 * (bf2f(h2v.z) + bf2f(l2v.z));
    o.w = b0 * (bf2f(h1v.w) + bf2f(l1v.w)) + b1 * (bf2f(h2v.w) + bf2f(l2v.w));
    *reinterpret_cast<float4*>(out + base) = o;
}

// ---------------------------------------------------------------------------
extern "C" void kernel_launch(void* const* d_in, const int* in_sizes, int n_in,
                              void* d_out, int out_size, void* d_ws, size_t ws_size,
                              hipStream_t stream) {
    const float* embed_h = (const float*)d_in[0];
    const float* gru_h   = (const float*)d_in[1];
    const float* embed_o = (const float*)d_in[2];
    const float* gru_o   = (const float*)d_in[3];
    const float* W_src1  = (const float*)d_in[4];
    const float* W_dst1  = (const float*)d_in[5];
    const float* a1      = (const float*)d_in[6];
    const float* W_in2   = (const float*)d_in[7];
    const float* a2      = (const float*)d_in[8];
    const float* Wp1     = (const float*)d_in[9];
    const float* bp1     = (const float*)d_in[10];
    const float* wp2     = (const float*)d_in[11];
    const int*   e1_src  = (const int*)d_in[12];
    const int*   e2_src  = (const int*)d_in[14];
    float* out = (float*)d_out;

    float* ws = (float*)d_ws;
    // all ushort regions, non-overlapping, in float-offset units:
    unsigned short* zbf  = (unsigned short*)ws;                        // [0, .5Z)
    unsigned short* z2bf = (unsigned short*)(ws + (size_t)ZEL / 2);    // [.5Z, Z)
    unsigned short* hhi1 = (unsigned short*)(ws + (size_t)ZEL);        // [Z, 1.5Z)
    unsigned short* hlo1 = (unsigned short*)(ws + (size_t)3 * ZEL / 2);
    unsigned short* hhi2 = (unsigned short*)(ws + (size_t)2 * ZEL);
    unsigned short* hlo2 = (unsigned short*)(ws + (size_t)5 * ZEL / 2);

    float* tail  = ws + (size_t)3 * ZEL;
    float* ssrc  = tail;
    float* sdst  = ssrc + NN * 4;
    float* ssrc2 = ssrc + NN * 8;
    float* sdst2 = ssrc + NN * 12;
    float* u1    = ssrc + NN * 16;
    float* u2    = u1 + 1024;
    float* wacc  = u2 + 1024;
    unsigned short* Bhi1 = (unsigned short*)(wacc + 2);
    unsigned short* Blo1 = Bhi1 + 65536;
    unsigned short* Bhi2 = Blo1 + 65536;
    unsigned short* Blo2 = Bhi2 + 65536;
    unsigned short* Bhip = Blo2 + 65536;
    unsigned short* Blop = Bhip + 65536;

    convert_w<<<256, 256, 0, stream>>>(W_src1, 0, Bhi1, Blo1);
    convert_w<<<256, 256, 0, stream>>>(W_in2,  0, Bhi2, Blo2);
    convert_w<<<256, 256, 0, stream>>>(Wp1,    1, Bhip, Blop);
    prep_u<<<1, 256, 0, stream>>>(W_dst1, a1, u1);
    prep_u<<<1, 256, 0, stream>>>(W_in2,  a2, u2);

    gemm_nodes<<<NB1, 256, 0, stream>>>(embed_h, gru_h, Bhi1, Blo1, a1,
                                        zbf, ssrc, nullptr, nullptr, nullptr, nullptr);
    gemm_nodes<<<NB1, 256, 0, stream>>>(embed_o, gru_o, Bhi2, Blo2, a2,
                                        z2bf, ssrc2, u1, u2, sdst, sdst2);

    int wave_blocks = (NN * 64 + 255) / 256;
    agg_kernel<<<wave_blocks, 256, 0, stream>>>(zbf, ssrc, sdst, e1_src, hhi1, hlo1);
    agg_kernel<<<wave_blocks, 256, 0, stream>>>(z2bf, ssrc2, sdst2, e2_src, hhi2, hlo2);

    hipMemsetAsync(wacc, 0, 2 * sizeof(float), stream);
    gemm_proj<<<2 * NB1, 256, 0, stream>>>(hhi1, hlo1, hhi2, hlo2,
                                           Bhip, Blop, bp1, wp2, wacc);

    combine_kernel<<<(NN * 64 + 255) / 256, 256, 0, stream>>>(hhi1, hlo1, hhi2, hlo2,
                                                              wacc, out);
}

// Round 12
// 327.441 us; speedup vs baseline: 2.1273x; 1.0385x over previous
//
#include <hip/hip_runtime.h>
#include <hip/hip_bf16.h>

#define NN 30000          // N_H == N_O
#define DEG 16
#define ZEL (NN * 256)    // elements per node-feature matrix
#define NB1 469           // ceil(NN/64)

typedef __attribute__((ext_vector_type(8))) short bf16x8_t;
typedef __attribute__((ext_vector_type(4))) float f32x4_t;

// ---- bf16 bit helpers (RNE) ----------------------------------------------
__device__ __forceinline__ unsigned short f2bf(float x) {
    unsigned u = __float_as_uint(x);
    return (unsigned short)((u + 0x7FFFu + ((u >> 16) & 1u)) >> 16);
}
__device__ __forceinline__ float bf2f(unsigned short b) {
    return __uint_as_float(((unsigned)b) << 16);
}

// ---- async global->LDS 16B copy ------------------------------------------
__device__ __forceinline__ void gl_lds16(const void* g, void* l) {
    __builtin_amdgcn_global_load_lds(
        (const __attribute__((address_space(1))) unsigned int*)g,
        (__attribute__((address_space(3))) unsigned int*)l, 16, 0, 0);
}

// ---------------------------------------------------------------------------
// Weight -> LDS-image hi/lo bf16 layout.
//   o = kk*8192 + ct*512 + g*128 + r*8 + j  (kk=d>>5, g=(d>>3)&3, j=d&7,
//                                            ct=c>>4, r=c&15)
__global__ void convert_w(const float* __restrict__ W, int isWp,
                          unsigned short* __restrict__ Bhi,
                          unsigned short* __restrict__ Blo) {
    int idx = blockIdx.x * 256 + threadIdx.x;
    if (idx >= 65536) return;
    int d = idx >> 8, c = idx & 255;
    float x;
    if (isWp) x = W[d * 256 + c];
    else { int h = c >> 6, k = c & 63; x = W[h * 16384 + d * 64 + k]; }
    unsigned short hh = f2bf(x);
    unsigned short ll = f2bf(x - bf2f(hh));
    int o = (d >> 5) * 8192 + (c >> 4) * 512 + ((d >> 3) & 3) * 128
          + (c & 15) * 8 + (d & 7);
    Bhi[o] = hh; Blo[o] = ll;
}

// ---------------------------------------------------------------------------
// u[h*256+d] = sum_k W[h][d][k] * a[h*128 + 64 + k]
__global__ void prep_u(const float* __restrict__ W, const float* __restrict__ a,
                       float* __restrict__ u) {
    int t = threadIdx.x;
    for (int idx = t; idx < 1024; idx += blockDim.x) {
        int h = idx >> 8, d = idx & 255;
        const float* wp = W + (h * 256 + d) * 64;
        const float* ap = a + h * 128 + 64;
        float s = 0.f;
        #pragma unroll 8
        for (int k = 0; k < 64; ++k) s += wp[k] * ap[k];
        u[idx] = s;
    }
}

// ---- stage one 16KB hi + 16KB lo slab of B into LDS (async) ---------------
__device__ __forceinline__ void stage_slab(const unsigned short* __restrict__ Bhi,
                                           const unsigned short* __restrict__ Blo,
                                           int kk, unsigned char* smem,
                                           unsigned boff, int t) {
    #pragma unroll
    for (int rd = 0; rd < 4; ++rd) {
        gl_lds16(Bhi + kk * 8192 + rd * 2048 + t * 8,
                 smem + boff + rd * 4096 + t * 16);
        gl_lds16(Blo + kk * 8192 + rd * 2048 + t * 8,
                 smem + boff + 16384 + rd * 4096 + t * 16);
    }
}

// ---- hi-only slab stage (16KB) -------------------------------------------
__device__ __forceinline__ void stage_slab1(const unsigned short* __restrict__ B,
                                            int kk, unsigned char* smem,
                                            unsigned boff, int t) {
    #pragma unroll
    for (int rd = 0; rd < 4; ++rd) {
        gl_lds16(B + kk * 8192 + rd * 2048 + t * 8,
                 smem + boff + rd * 4096 + t * 16);
    }
}

// ---------------------------------------------------------------------------
// z(bf16) = concat(f1,f2) @ B  (bf16-split MFMA). A in regs, B LDS-staged.
// Fused: s_src = z·aL (f32 acc); sd1/sd2 = A·u (call 2).
__global__ __launch_bounds__(256)
void gemm_nodes(const float* __restrict__ f1, const float* __restrict__ f2,
                const unsigned short* __restrict__ Bhi,
                const unsigned short* __restrict__ Blo,
                const float* __restrict__ aL,
                unsigned short* __restrict__ z, float* __restrict__ s_src,
                const float* __restrict__ u1, const float* __restrict__ u2,
                float* __restrict__ sd1, float* __restrict__ sd2) {
    __shared__ unsigned char smem[65536];       // 2 bufs x (16KB hi + 16KB lo)
    int t = threadIdx.x, l = t & 63, wv = t >> 6;
    int g = l >> 4, r = l & 15;
    int row0 = blockIdx.x * 64 + wv * 16;
    bool vrow = (row0 + r) < NN;
    int arow = row0 + r; if (arow >= NN) arow = NN - 1;

    stage_slab(Bhi, Blo, 0, smem, 0, t);        // issue earliest

    // ---- prefetch ALL A fragments ----
    float4 af[8][2];
    #pragma unroll
    for (int kk = 0; kk < 8; ++kk) {
        int k0 = kk * 32 + g * 8;
        const float* ap = (k0 < 128) ? (f1 + arow * 128 + k0)
                                     : (f2 + arow * 128 + (k0 - 128));
        af[kk][0] = *reinterpret_cast<const float4*>(ap);
        af[kk][1] = *reinterpret_cast<const float4*>(ap + 4);
    }

    // ---- fused dst scores from raw A (call 2 only) ----
    if (u1) {
        float pd1[4] = {0.f,0.f,0.f,0.f}, pd2[4] = {0.f,0.f,0.f,0.f};
        #pragma unroll
        for (int kk = 0; kk < 8; ++kk) {
            int k0 = kk * 32 + g * 8;
            #pragma unroll
            for (int h = 0; h < 4; ++h) {
                float4 ua = *reinterpret_cast<const float4*>(u1 + h * 256 + k0);
                float4 ub = *reinterpret_cast<const float4*>(u1 + h * 256 + k0 + 4);
                pd1[h] += af[kk][0].x*ua.x + af[kk][0].y*ua.y + af[kk][0].z*ua.z + af[kk][0].w*ua.w
                        + af[kk][1].x*ub.x + af[kk][1].y*ub.y + af[kk][1].z*ub.z + af[kk][1].w*ub.w;
                float4 va = *reinterpret_cast<const float4*>(u2 + h * 256 + k0);
                float4 vb = *reinterpret_cast<const float4*>(u2 + h * 256 + k0 + 4);
                pd2[h] += af[kk][0].x*va.x + af[kk][0].y*va.y + af[kk][0].z*va.z + af[kk][0].w*va.w
                        + af[kk][1].x*vb.x + af[kk][1].y*vb.y + af[kk][1].z*vb.z + af[kk][1].w*vb.w;
            }
        }
        #pragma unroll
        for (int m = 16; m < 64; m <<= 1) {
            #pragma unroll
            for (int h = 0; h < 4; ++h) {
                pd1[h] += __shfl_xor(pd1[h], m, 64);
                pd2[h] += __shfl_xor(pd2[h], m, 64);
            }
        }
        if (g == 0 && vrow) {
            #pragma unroll
            for (int h = 0; h < 4; ++h) sd1[arow * 4 + h] = pd1[h];
        }
        if (g == 1 && vrow) {
            #pragma unroll
            for (int h = 0; h < 4; ++h) sd2[arow * 4 + h] = pd2[h];
        }
    }

    // ---- convert A to bf16 hi/lo fragments ----
    bf16x8_t ah[8], al[8];
    #pragma unroll
    for (int kk = 0; kk < 8; ++kk) {
        float xs[8] = {af[kk][0].x, af[kk][0].y, af[kk][0].z, af[kk][0].w,
                       af[kk][1].x, af[kk][1].y, af[kk][1].z, af[kk][1].w};
        #pragma unroll
        for (int j = 0; j < 8; ++j) {
            unsigned short h = f2bf(xs[j]);
            ah[kk][j] = (short)h;
            al[kk][j] = (short)f2bf(xs[j] - bf2f(h));
        }
    }

    f32x4_t acc[16];
    #pragma unroll
    for (int ct = 0; ct < 16; ++ct) acc[ct] = (f32x4_t){0.f, 0.f, 0.f, 0.f};

    // ---- main loop: one barrier per kk, B from LDS (dbuf) ----
    #pragma unroll
    for (int kk = 0; kk < 8; ++kk) {
        __syncthreads();
        if (kk < 7) stage_slab(Bhi, Blo, kk + 1, smem, ((kk + 1) & 1) * 32768u, t);
        const unsigned char* bufp = smem + (kk & 1) * 32768u;
        #pragma unroll
        for (int ct = 0; ct < 16; ++ct) {
            bf16x8_t bhv = *reinterpret_cast<const bf16x8_t*>(bufp + ct * 1024 + l * 16);
            bf16x8_t blv = *reinterpret_cast<const bf16x8_t*>(bufp + 16384 + ct * 1024 + l * 16);
            acc[ct] = __builtin_amdgcn_mfma_f32_16x16x32_bf16(ah[kk], bhv, acc[ct], 0, 0, 0);
            acc[ct] = __builtin_amdgcn_mfma_f32_16x16x32_bf16(ah[kk], blv, acc[ct], 0, 0, 0);
            acc[ct] = __builtin_amdgcn_mfma_f32_16x16x32_bf16(al[kk], bhv, acc[ct], 0, 0, 0);
        }
    }

    // ---- z write (bf16) ----
    int r0 = row0 + g * 4;
    #pragma unroll
    for (int ct = 0; ct < 16; ++ct) {
        int col = ct * 16 + r;
        #pragma unroll
        for (int i = 0; i < 4; ++i) {
            int row = r0 + i;
            if (row < NN) z[row * 256 + col] = f2bf(acc[ct][i]);
        }
    }

    // ---- fused s_src = z · aL (from f32 acc) ----
    float sc[16];
    #pragma unroll
    for (int j = 0; j < 16; ++j) sc[j] = 0.f;
    #pragma unroll
    for (int ct = 0; ct < 16; ++ct) {
        int h = ct >> 2;
        float coef = aL[h * 128 + (ct & 3) * 16 + r];
        #pragma unroll
        for (int i = 0; i < 4; ++i) sc[h * 4 + i] += acc[ct][i] * coef;
    }
    #pragma unroll
    for (int m = 1; m < 16; m <<= 1) {
        #pragma unroll
        for (int j = 0; j < 16; ++j) sc[j] += __shfl_xor(sc[j], m, 64);
    }
    {
        int h = r >> 2, i = r & 3;
        int row = row0 + g * 4 + i;
        if (row < NN) s_src[row * 4 + h] = sc[r];
    }
}

// ---------------------------------------------------------------------------
// agg: one wave per dst node; z gathered as bf16 (half bytes); out hi/lo bf16.
__global__ __launch_bounds__(256)
void agg_kernel(const unsigned short* __restrict__ z, const float* __restrict__ s_src,
                const float* __restrict__ s_dst, const int* __restrict__ esrc,
                unsigned short* __restrict__ ohi, unsigned short* __restrict__ olo) {
    int wid = (blockIdx.x * blockDim.x + threadIdx.x) >> 6;
    int lane = threadIdx.x & 63;
    if (wid >= NN) return;
    int h = lane >> 4;
    int e = lane & 15;
    int src = esrc[wid * 16 + e];
    float x = s_src[src * 4 + h] + s_dst[wid * 4 + h];
    x = (x >= 0.f) ? x : 0.01f * x;
    float m = x;
    #pragma unroll
    for (int d = 1; d < 16; d <<= 1) m = fmaxf(m, __shfl_xor(m, d, 64));
    float p = __expf(x - m);
    float s = p;
    #pragma unroll
    for (int d = 1; d < 16; d <<= 1) s += __shfl_xor(s, d, 64);
    float alpha = p / s;

    int c = h * 64 + e * 4;
    int gbase = lane & 48;
    float4 acc = make_float4(0.f, 0.f, 0.f, 0.f);
    #pragma unroll
    for (int t = 0; t < 16; ++t) {
        float a = __shfl(alpha, gbase | t, 64);
        int sidx = __shfl(src, gbase | t, 64);
        ushort4 v = *reinterpret_cast<const ushort4*>(z + sidx * 256 + c);
        acc.x += a * bf2f(v.x); acc.y += a * bf2f(v.y);
        acc.z += a * bf2f(v.z); acc.w += a * bf2f(v.w);
    }
    int base = wid * 256 + c;
    ushort4 hv, lv;
    hv.x = f2bf(acc.x); lv.x = f2bf(acc.x - bf2f(hv.x));
    hv.y = f2bf(acc.y); lv.y = f2bf(acc.y - bf2f(hv.y));
    hv.z = f2bf(acc.z); lv.z = f2bf(acc.z - bf2f(hv.z));
    hv.w = f2bf(acc.w); lv.w = f2bf(acc.w - bf2f(hv.w));
    *reinterpret_cast<ushort4*>(ohi + base) = hv;
    *reinterpret_cast<ushort4*>(olo + base) = lv;
}

// ---------------------------------------------------------------------------
// proj (single-bf16): blocks [0,NB1)->h1(hi), [NB1,2NB1)->h2(hi).
// Error feeds only the scalar beta (mean over 30000 rows) -> negligible.
__global__ __launch_bounds__(256)
void gemm_proj(const unsigned short* __restrict__ hhi1,
               const unsigned short* __restrict__ hhi2,
               const unsigned short* __restrict__ Bhi,
               const float* __restrict__ bp, const float* __restrict__ wp2v,
               float* __restrict__ wacc) {
    __shared__ unsigned char smem[32768];       // 2 bufs x 16KB (hi only)
    int t = threadIdx.x, l = t & 63, wv = t >> 6;
    int g = l >> 4, r = l & 15;
    int bid = blockIdx.x;
    int e = (bid >= NB1) ? 1 : 0;
    int nb = bid - e * NB1;
    const unsigned short* Ah = e ? hhi2 : hhi1;
    int n0 = nb * 64 + wv * 16;
    int nA = n0 + r; if (nA >= NN) nA = NN - 1;
    const unsigned short* Ahp = Ah + (size_t)nA * 256;

    stage_slab1(Bhi, 0, smem, 0, t);

    bf16x8_t ahf[8];
    #pragma unroll
    for (int kk = 0; kk < 8; ++kk)
        ahf[kk] = *reinterpret_cast<const bf16x8_t*>(Ahp + kk * 32 + g * 8);

    f32x4_t acc[16];
    #pragma unroll
    for (int ct = 0; ct < 16; ++ct) acc[ct] = (f32x4_t){0.f, 0.f, 0.f, 0.f};

    #pragma unroll
    for (int kk = 0; kk < 8; ++kk) {
        __syncthreads();
        if (kk < 7) stage_slab1(Bhi, kk + 1, smem, ((kk + 1) & 1) * 16384u, t);
        const unsigned char* bufp = smem + (kk & 1) * 16384u;
        #pragma unroll
        for (int ct = 0; ct < 16; ++ct) {
            bf16x8_t bhv = *reinterpret_cast<const bf16x8_t*>(bufp + ct * 1024 + l * 16);
            acc[ct] = __builtin_amdgcn_mfma_f32_16x16x32_bf16(ahf[kk], bhv, acc[ct], 0, 0, 0);
        }
    }

    float part = 0.f;
    #pragma unroll
    for (int ct = 0; ct < 16; ++ct) {
        int col = ct * 16 + r;
        float b = bp[col], w = wp2v[col];
        #pragma unroll
        for (int i = 0; i < 4; ++i) {
            int n = n0 + g * 4 + i;
            if (n < NN) {
                float x = acc[ct][i] + b;
                float tnh = 1.f - 2.f / (__expf(2.f * x) + 1.f);
                part += tnh * w;
            }
        }
    }
    #pragma unroll
    for (int d = 1; d < 64; d <<= 1) part += __shfl_xor(part, d, 64);
    __shared__ float red[4];
    if (l == 0) red[wv] = part;
    __syncthreads();
    if (t == 0) atomicAdd(wacc + e, red[0] + red[1] + red[2] + red[3]);
}

// ---------------------------------------------------------------------------
__global__ __launch_bounds__(256)
void combine_kernel(const unsigned short* __restrict__ hhi1, const unsigned short* __restrict__ hlo1,
                    const unsigned short* __restrict__ hhi2, const unsigned short* __restrict__ hlo2,
                    const float* __restrict__ wacc, float* __restrict__ out) {
    int idx = blockIdx.x * blockDim.x + threadIdx.x;
    if (idx >= NN * 64) return;
    float w0 = wacc[0] * (1.f / 30000.f), w1 = wacc[1] * (1.f / 30000.f);
    float mx = fmaxf(w0, w1);
    float e0 = __expf(w0 - mx), e1 = __expf(w1 - mx);
    float inv = 1.f / (e0 + e1);
    float b0 = e0 * inv, b1 = e1 * inv;
    int base = idx * 4;
    ushort4 h1v = *reinterpret_cast<const ushort4*>(hhi1 + base);
    ushort4 l1v = *reinterpret_cast<const ushort4*>(hlo1 + base);
    ushort4 h2v = *reinterpret_cast<const ushort4*>(hhi2 + base);
    ushort4 l2v = *reinterpret_cast<const ushort4*>(hlo2 + base);
    float4 o;
    o.x = b0 * (bf2f(h1v.x) + bf2f(l1v.x)) + b1 * (bf2f(h2v.x) + bf2f(l2v.x));
    o.y = b0 * (bf2f(h1v.y) + bf2f(l1v.y)) + b1 * (bf2f(h2v.y) + bf2f(l2v.y));
    o.z = b0 * (bf2f(h1v.z) + bf2f(l1v.z)) + b1 * (bf2f(h2v.z) + bf2f(l2v.z));
    o.w = b0 * (bf2f(h1v.w) + bf2f(l1v.w)) + b1 * (bf2f(h2v.w) + bf2f(l2v.w));
    *reinterpret_cast<float4*>(out + base) = o;
}

// ---------------------------------------------------------------------------
extern "C" void kernel_launch(void* const* d_in, const int* in_sizes, int n_in,
                              void* d_out, int out_size, void* d_ws, size_t ws_size,
                              hipStream_t stream) {
    const float* embed_h = (const float*)d_in[0];
    const float* gru_h   = (const float*)d_in[1];
    const float* embed_o = (const float*)d_in[2];
    const float* gru_o   = (const float*)d_in[3];
    const float* W_src1  = (const float*)d_in[4];
    const float* W_dst1  = (const float*)d_in[5];
    const float* a1      = (const float*)d_in[6];
    const float* W_in2   = (const float*)d_in[7];
    const float* a2      = (const float*)d_in[8];
    const float* Wp1     = (const float*)d_in[9];
    const float* bp1     = (const float*)d_in[10];
    const float* wp2     = (const float*)d_in[11];
    const int*   e1_src  = (const int*)d_in[12];
    const int*   e2_src  = (const int*)d_in[14];
    float* out = (float*)d_out;

    float* ws = (float*)d_ws;
    unsigned short* zbf  = (unsigned short*)ws;                        // [0, .5Z)
    unsigned short* z2bf = (unsigned short*)(ws + (size_t)ZEL / 2);    // [.5Z, Z)
    unsigned short* hhi1 = (unsigned short*)(ws + (size_t)ZEL);        // [Z, 1.5Z)
    unsigned short* hlo1 = (unsigned short*)(ws + (size_t)3 * ZEL / 2);
    unsigned short* hhi2 = (unsigned short*)(ws + (size_t)2 * ZEL);
    unsigned short* hlo2 = (unsigned short*)(ws + (size_t)5 * ZEL / 2);

    float* tail  = ws + (size_t)3 * ZEL;
    float* ssrc  = tail;
    float* sdst  = ssrc + NN * 4;
    float* ssrc2 = ssrc + NN * 8;
    float* sdst2 = ssrc + NN * 12;
    float* u1    = ssrc + NN * 16;
    float* u2    = u1 + 1024;
    float* wacc  = u2 + 1024;
    unsigned short* Bhi1 = (unsigned short*)(wacc + 2);
    unsigned short* Blo1 = Bhi1 + 65536;
    unsigned short* Bhi2 = Blo1 + 65536;
    unsigned short* Blo2 = Bhi2 + 65536;
    unsigned short* Bhip = Blo2 + 65536;
    unsigned short* Blop = Bhip + 65536;

    convert_w<<<256, 256, 0, stream>>>(W_src1, 0, Bhi1, Blo1);
    convert_w<<<256, 256, 0, stream>>>(W_in2,  0, Bhi2, Blo2);
    convert_w<<<256, 256, 0, stream>>>(Wp1,    1, Bhip, Blop);
    prep_u<<<1, 256, 0, stream>>>(W_dst1, a1, u1);
    prep_u<<<1, 256, 0, stream>>>(W_in2,  a2, u2);

    gemm_nodes<<<NB1, 256, 0, stream>>>(embed_h, gru_h, Bhi1, Blo1, a1,
                                        zbf, ssrc, nullptr, nullptr, nullptr, nullptr);
    gemm_nodes<<<NB1, 256, 0, stream>>>(embed_o, gru_o, Bhi2, Blo2, a2,
                                        z2bf, ssrc2, u1, u2, sdst, sdst2);

    int wave_blocks = (NN * 64 + 255) / 256;
    agg_kernel<<<wave_blocks, 256, 0, stream>>>(zbf, ssrc, sdst, e1_src, hhi1, hlo1);
    agg_kernel<<<wave_blocks, 256, 0, stream>>>(z2bf, ssrc2, sdst2, e2_src, hhi2, hlo2);

    hipMemsetAsync(wacc, 0, 2 * sizeof(float), stream);
    gemm_proj<<<2 * NB1, 256, 0, stream>>>(hhi1, hhi2, Bhip, bp1, wp2, wacc);

    combine_kernel<<<(NN * 64 + 255) / 256, 256, 0, stream>>>(hhi1, hlo1, hhi2, hlo2,
                                                              wacc, out);
}